// Round 8
// baseline (733.824 us; speedup 1.0000x reference)
//
#include <hip/hip_runtime.h>
#include <cstdint>
#include <cstddef>

#define N_NODES 16384
#define N_EDGES 65536
#define ETOT    81920
#define B_GR    32

typedef __attribute__((ext_vector_type(8))) short bf16x8;
typedef __attribute__((ext_vector_type(4))) float f32x4;

// ---------------- workspace layout (bytes), peak 138,285,056 ----------------
static constexpr size_t OFF_XL    = 0;              // 33,554,432
static constexpr size_t OFF_XR    = 33554432ULL;    // 33,554,432 (gat_bf aliases)
static constexpr size_t OFF_EBF   = 67108864ULL;    // 67,108,864  E_bf
static constexpr size_t OFF_HBF   = 67108864ULL;    //   alias: h_bf (dead after xlxr GEMM)
static constexpr size_t OFF_WCAT  = 83886080ULL;    //   alias: Wcat (dead after xlxr GEMM)
static constexpr size_t OFF_ROWP  = 67108864ULL;    //   alias: rowptr (after k_mfma_we)
static constexpr size_t OFF_CSR   = 67174656ULL;    //   alias
static constexpr size_t OFF_ALPHA = 67502336ULL;    //   alias
static constexpr size_t OFF_WGEP  = 134217728ULL;   // 1,048,576
static constexpr size_t OFF_LPART = 135266304ULL;   // 2,097,152  logit_part [65536x8 f32]
// ---- zero zone (720,896 B) ----
static constexpr size_t OFF_DEG   = 137363456ULL;
static constexpr size_t OFF_ODEG  = 137428992ULL;
static constexpr size_t OFF_CURS  = 137494528ULL;
static constexpr size_t OFF_PG    = 137560064ULL;
static constexpr size_t OFF_PDG   = 137691136ULL;
static constexpr size_t OFF_PGAT  = 137822208ULL;
static constexpr size_t OFF_PS    = 137953280ULL;
static constexpr size_t OFF_PE    = 138018816ULL;
// ---- end zero zone ----
static constexpr size_t OFF_WLOOP = 138084352ULL;
static constexpr size_t OFF_YG    = 138088448ULL;
static constexpr size_t OFF_PN    = 138153984ULL;
// end = 138,285,056

__device__ __forceinline__ float leaky01(float v){ return v >= 0.f ? v : 0.01f*v; }
__device__ __forceinline__ float leaky02(float v){ return v >= 0.f ? v : 0.2f*v; }
__device__ __forceinline__ unsigned short f2bf(float f){
  union { float f; unsigned u; } v; v.f = f;
  unsigned r = v.u + 0x7FFFu + ((v.u >> 16) & 1u);
  return (unsigned short)(r >> 16);
}
__device__ __forceinline__ float bf2f(unsigned short h){
  union { unsigned u; float f; } v; v.u = ((unsigned)h) << 16;
  return v.f;
}

// ---------------- merged prep ----------------
__global__ __launch_bounds__(256) void k_prep0(
    const float* __restrict__ x, const float* __restrict__ Wn, const float* __restrict__ bn,
    const float* __restrict__ Wl, const float* __restrict__ Wr,
    const float* __restrict__ Wge, const float* __restrict__ y,
    const float* __restrict__ Wg, const float* __restrict__ bg,
    const float* __restrict__ We, const float* __restrict__ be,
    float* __restrict__ zone, unsigned short* __restrict__ h_bf,
    unsigned short* __restrict__ Wcat, unsigned short* __restrict__ Wge_p,
    float* __restrict__ yg, float* __restrict__ we_loop) {
  __shared__ float e_lds[512];
  int bx = blockIdx.x, tid = threadIdx.x;
  if (bx < 176) {
    ((float4*)zone)[bx*256 + tid] = (float4){0.f,0.f,0.f,0.f};
  } else if (bx < 1200) {               // h_bf
    int gid = (bx-176)*256 + tid;
    int base = gid*8;
    int n = base >> 9, j = base & 511;
    float xv = x[n];
    float4 w0 = *(const float4*)(Wn + j);
    float4 w1 = *(const float4*)(Wn + j + 4);
    float4 b0 = *(const float4*)(bn + j);
    float4 b1 = *(const float4*)(bn + j + 4);
    unsigned short o[8];
    o[0]=f2bf(leaky01(xv*w0.x+b0.x)); o[1]=f2bf(leaky01(xv*w0.y+b0.y));
    o[2]=f2bf(leaky01(xv*w0.z+b0.z)); o[3]=f2bf(leaky01(xv*w0.w+b0.w));
    o[4]=f2bf(leaky01(xv*w1.x+b1.x)); o[5]=f2bf(leaky01(xv*w1.y+b1.y));
    o[6]=f2bf(leaky01(xv*w1.z+b1.z)); o[7]=f2bf(leaky01(xv*w1.w+b1.w));
    ((uint4*)h_bf)[gid] = *(const uint4*)o;
  } else if (bx < 2224) {               // Wcat
    int i = (bx-1200)*256 + tid;
    int base = i*4;
    const float* src = (base < 524288) ? (Wl + base) : (Wr + base - 524288);
    float4 v = *(const float4*)src;
    ushort4 o; o.x=f2bf(v.x); o.y=f2bf(v.y); o.z=f2bf(v.z); o.w=f2bf(v.w);
    ((ushort4*)Wcat)[i] = o;
  } else if (bx < 4272) {               // Wge_p
    int gid = (bx-2224)*256 + tid;
    int j = gid >> 9, k = gid & 511;
    Wge_p[gid] = (k < 511) ? f2bf(Wge[(size_t)j*511 + k]) : (unsigned short)0;
  } else if (bx < 4336) {               // yg
    int gid = (bx-4272)*256 + tid;
    int b = gid >> 9, j = gid & 511;
    float s = bg[j];
    #pragma unroll
    for (int k=0;k<5;k++) s += y[b*5+k]*Wg[j*5+k];
    yg[gid] = leaky01(s);
  } else {                              // we_loop
    for (int c = tid; c < 512; c += 256) {
      float v = 0.f;
      if (c < 511) {
        float s = be[c];
        #pragma unroll
        for (int q=0;q<5;q++) s += We[c*5+q];
        v = leaky01(s);
      }
      e_lds[c] = v;
    }
    __syncthreads();
    int j = (bx-4336)*256 + tid;
    float s = 0.f;
    for (int k=0;k<511;k++) s += e_lds[k]*Wge[(size_t)j*511+k];
    we_loop[j] = s;
  }
}

// ---------------- E_bf prep ----------------
__global__ __launch_bounds__(256) void k_prep_e(
    const float* __restrict__ ea, const float* __restrict__ We, const float* __restrict__ be,
    unsigned short* __restrict__ E_bf) {
  int gid = blockIdx.x*256 + threadIdx.x;
  int e = gid >> 6, cg = gid & 63;
  int c0 = cg*8;
  const float* e5 = ea + (size_t)e*5;
  float a0=e5[0], a1=e5[1], a2=e5[2], a3=e5[3], a4=e5[4];
  unsigned short o[8];
  #pragma unroll
  for (int j=0;j<8;j++) {
    int c = c0 + j;
    float v = 0.f;
    if (c < 511) {
      const float* w = We + c*5;
      float s = be[c] + a0*w[0] + a1*w[1] + a2*w[2] + a3*w[3] + a4*w[4];
      v = leaky01(s);
    }
    o[j] = f2bf(v);
  }
  ((uint4*)E_bf)[gid] = *(const uint4*)o;
}

// ---------------- CSR build ----------------
__global__ void k_deg(const int* __restrict__ ei, int* __restrict__ deg, int* __restrict__ odeg) {
  int i = blockIdx.x*blockDim.x + threadIdx.x;
  int s, d;
  if (i < N_EDGES) { s = ei[i]; d = ei[N_EDGES + i]; }
  else { s = i - N_EDGES; d = s; }
  atomicAdd(&deg[d], 1);
  atomicAdd(&odeg[s], 1);
}

__global__ __launch_bounds__(1024) void k_scan(const int* __restrict__ deg, int* __restrict__ rowptr) {
  __shared__ int sums[1024];
  int t = threadIdx.x;
  int local[16]; int s = 0;
  #pragma unroll
  for (int i=0;i<16;i++){ local[i] = deg[t*16+i]; s += local[i]; }
  sums[t] = s; __syncthreads();
  for (int off=1; off<1024; off<<=1) {
    int v = (t >= off) ? sums[t-off] : 0;
    __syncthreads();
    sums[t] += v;
    __syncthreads();
  }
  int run = (t==0) ? 0 : sums[t-1];
  if (t==0) rowptr[0] = 0;
  #pragma unroll
  for (int i=0;i<16;i++){ run += local[i]; rowptr[t*16+i+1] = run; }
}

__global__ void k_fill_csr(const int* __restrict__ ei, const int* __restrict__ rowptr,
                           int* __restrict__ cursor, int* __restrict__ csr) {
  int i = blockIdx.x*blockDim.x + threadIdx.x;
  int d = (i < N_EDGES) ? ei[N_EDGES + i] : (i - N_EDGES);
  int pos = rowptr[d] + atomicAdd(&cursor[d], 1);
  csr[pos] = i;
}

// ================= MFMA GEMM core: A via dbuf LDS, B direct from global (L2) =================

// ---------------- combined xl/xr MFMA GEMM ----------------
__global__ __launch_bounds__(256) void k_gemm_xlxr(
    const unsigned short* __restrict__ h_bf, const unsigned short* __restrict__ Wcat,
    const float* __restrict__ bl, const float* __restrict__ br,
    unsigned short* __restrict__ xl_bf, unsigned short* __restrict__ xr_bf) {
  __shared__ unsigned short As[2][4096];
  int blk = blockIdx.x;
  int xcd = blk & 7, slot = blk >> 3;
  int bx = xcd*16 + (slot >> 4), by = slot & 15;
  int row0 = bx*128, col0 = by*128;
  int tid = threadIdx.x;
  int w = tid >> 6, lane = tid & 63;
  int wm = w >> 1, wn = w & 1;
  int quad = lane >> 4, l16 = lane & 15;
  int ldoff = w*512 + lane*8;
  const unsigned short* gA = h_bf + (size_t)(row0 + w*16 + l16)*512 + quad*8;
  const unsigned short* gB = Wcat + (size_t)(col0 + wn*64 + l16)*512 + quad*8;
  f32x4 acc[4][4];
  #pragma unroll
  for (int i=0;i<4;i++)
    #pragma unroll
    for (int j=0;j<4;j++) acc[i][j] = (f32x4){0.f,0.f,0.f,0.f};

  {
    uint4 a0 = *(const uint4*)(gA);
    uint4 a1 = *(const uint4*)(gA + 32768);
    *(uint4*)&As[0][ldoff] = a0; *(uint4*)&As[0][2048+ldoff] = a1;
  }
  __syncthreads();
  int cur = 0;
  #pragma unroll 2
  for (int k0 = 32; k0 <= 512; k0 += 32) {
    uint4 na0, na1;
    bool more = (k0 < 512);
    if (more) {
      na0 = *(const uint4*)(gA + k0);
      na1 = *(const uint4*)(gA + 32768 + k0);
    }
    bf16x8 bfr[4];
    #pragma unroll
    for (int ni=0;ni<4;ni++)
      bfr[ni] = *(const bf16x8*)(gB + (size_t)ni*8192 + (k0 - 32));
    bf16x8 af[4];
    #pragma unroll
    for (int mi=0;mi<4;mi++)
      af[mi] = *(const bf16x8*)&As[cur][(wm*4+mi)*512 + quad*128 + l16*8];
    #pragma unroll
    for (int mi=0;mi<4;mi++)
      #pragma unroll
      for (int ni=0;ni<4;ni++)
        acc[mi][ni] = __builtin_amdgcn_mfma_f32_16x16x32_bf16(af[mi], bfr[ni], acc[mi][ni], 0, 0, 0);
    if (more) {
      *(uint4*)&As[cur^1][ldoff] = na0; *(uint4*)&As[cur^1][2048+ldoff] = na1;
    }
    __syncthreads();
    cur ^= 1;
  }
  bool isL = (by < 8);
  const float* bias = isL ? bl : br;
  unsigned short* O = isL ? xl_bf : xr_bf;
  int cb = isL ? col0 : (col0 - 1024);
  float bias4[4];
  #pragma unroll
  for (int ni=0;ni<4;ni++) bias4[ni] = bias[cb + wn*64 + ni*16 + l16];
  #pragma unroll
  for (int mi=0;mi<4;mi++)
    #pragma unroll
    for (int ni=0;ni<4;ni++) {
      int col = cb + wn*64 + ni*16 + l16;
      #pragma unroll
      for (int r=0;r<4;r++) {
        int row = row0 + wm*64 + mi*16 + quad*4 + r;
        O[(size_t)row*1024 + col] = f2bf(acc[mi][ni][r] + bias4[ni]);
      }
    }
}

// ---------------- we-GEMM + fused attention logits ----------------
// A via dbuf LDS; B direct from global; epilogue: 2-pass acc transpose
// through LDS + 16B coalesced xl/xr gathers + 4-lane reduce.
__global__ __launch_bounds__(256) void k_mfma_we(
    const unsigned short* __restrict__ E_bf, const unsigned short* __restrict__ Wge_bf,
    const int* __restrict__ ei,
    const unsigned short* __restrict__ xl_bf, const unsigned short* __restrict__ xr_bf,
    const float* __restrict__ att, float* __restrict__ logit_part) {
  __shared__ alignas(16) char smem[33280];          // union: As[2][4096] us | accT f32[64][130]
  unsigned short (*As)[4096] = (unsigned short (*)[4096])smem;
  float* accT = (float*)smem;
  int blk = blockIdx.x;
  int xcd = blk & 7, slot = blk >> 3;
  int bx = xcd*64 + (slot >> 3), by = slot & 7;
  int row0 = bx*128, col0 = by*128;
  int tid = threadIdx.x;
  int w = tid >> 6, lane = tid & 63;
  int wm = w >> 1, wn = w & 1;
  int quad = lane >> 4, l16 = lane & 15;
  int ldoff = w*512 + lane*8;
  const unsigned short* gA = E_bf  + (size_t)(row0 + w*16 + l16)*512 + quad*8;
  const unsigned short* gB = Wge_bf + (size_t)(col0 + wn*64 + l16)*512 + quad*8;
  f32x4 acc[4][4];
  #pragma unroll
  for (int i=0;i<4;i++)
    #pragma unroll
    for (int j=0;j<4;j++) acc[i][j] = (f32x4){0.f,0.f,0.f,0.f};

  {
    uint4 a0 = *(const uint4*)(gA);
    uint4 a1 = *(const uint4*)(gA + 32768);
    *(uint4*)&As[0][ldoff] = a0; *(uint4*)&As[0][2048+ldoff] = a1;
  }
  __syncthreads();
  int cur = 0;
  #pragma unroll 2
  for (int k0 = 32; k0 <= 512; k0 += 32) {
    uint4 na0, na1;
    bool more = (k0 < 512);
    if (more) {
      na0 = *(const uint4*)(gA + k0);
      na1 = *(const uint4*)(gA + 32768 + k0);
    }
    bf16x8 bfr[4];
    #pragma unroll
    for (int ni=0;ni<4;ni++)
      bfr[ni] = *(const bf16x8*)(gB + (size_t)ni*8192 + (k0 - 32));
    bf16x8 af[4];
    #pragma unroll
    for (int mi=0;mi<4;mi++)
      af[mi] = *(const bf16x8*)&As[cur][(wm*4+mi)*512 + quad*128 + l16*8];
    #pragma unroll
    for (int mi=0;mi<4;mi++)
      #pragma unroll
      for (int ni=0;ni<4;ni++)
        acc[mi][ni] = __builtin_amdgcn_mfma_f32_16x16x32_bf16(af[mi], bfr[ni], acc[mi][ni], 0, 0, 0);
    if (more) {
      *(uint4*)&As[cur^1][ldoff] = na0; *(uint4*)&As[cur^1][2048+ldoff] = na1;
    }
    __syncthreads();
    cur ^= 1;
  }
  // ---- epilogue: 2 passes over edge-halves ----
  int e_loc = tid >> 2, cq = tid & 3;
  #pragma unroll
  for (int eh = 0; eh < 2; eh++) {
    if (wm == eh) {
      #pragma unroll
      for (int mi=0;mi<4;mi++)
        #pragma unroll
        for (int ni=0;ni<4;ni++) {
          int colb = wn*64 + ni*16 + l16;
          #pragma unroll
          for (int r=0;r<4;r++)
            accT[(mi*16 + quad*4 + r)*130 + colb] = acc[mi][ni][r];
        }
    }
    __syncthreads();
    int e = row0 + eh*64 + e_loc;
    int s = ei[e], d = ei[N_EDGES + e];
    const uint4* xlp = (const uint4*)(xl_bf + (size_t)s*1024 + col0 + cq*32);
    const uint4* xrp = (const uint4*)(xr_bf + (size_t)d*1024 + col0 + cq*32);
    const float* accrow = accT + e_loc*130 + cq*32;
    const float* attp = att + col0 + cq*32;
    float p = 0.f;
    #pragma unroll
    for (int g=0; g<4; g++) {
      uint4 xa = xlp[g];
      uint4 xb = xrp[g];
      float4 at0 = *(const float4*)(attp + g*8);
      float4 at1 = *(const float4*)(attp + g*8 + 4);
      float4 ac0 = *(const float4*)(accrow + g*8);
      float4 ac1 = *(const float4*)(accrow + g*8 + 4);
      const unsigned short* ua = (const unsigned short*)&xa;
      const unsigned short* ub = (const unsigned short*)&xb;
      float z;
      z = ac0.x + bf2f(ua[0]) + bf2f(ub[0]); z = leaky02(z); p += z*at0.x;
      z = ac0.y + bf2f(ua[1]) + bf2f(ub[1]); z = leaky02(z); p += z*at0.y;
      z = ac0.z + bf2f(ua[2]) + bf2f(ub[2]); z = leaky02(z); p += z*at0.z;
      z = ac0.w + bf2f(ua[3]) + bf2f(ub[3]); z = leaky02(z); p += z*at0.w;
      z = ac1.x + bf2f(ua[4]) + bf2f(ub[4]); z = leaky02(z); p += z*at1.x;
      z = ac1.y + bf2f(ua[5]) + bf2f(ub[5]); z = leaky02(z); p += z*at1.y;
      z = ac1.z + bf2f(ua[6]) + bf2f(ub[6]); z = leaky02(z); p += z*at1.z;
      z = ac1.w + bf2f(ua[7]) + bf2f(ub[7]); z = leaky02(z); p += z*at1.w;
    }
    p += __shfl_down(p, 2, 4);
    p += __shfl_down(p, 1, 4);
    if (cq == 0) logit_part[(size_t)e*8 + by] = p;
    __syncthreads();
  }
}

// ---------------- fused: self-loop logit + softmax + GAT aggregation ----------------
__global__ __launch_bounds__(256) void k_softmax_gat(
    const int* __restrict__ ei, const int* __restrict__ rowptr, const int* __restrict__ csr,
    const float* __restrict__ logit_part,
    const unsigned short* __restrict__ xl_bf, const unsigned short* __restrict__ xr_bf,
    const float* __restrict__ we_loop, const float* __restrict__ att,
    const float* __restrict__ bgat,
    float* __restrict__ alpha, unsigned short* __restrict__ gat_bf) {
  __shared__ float sl[256];
  __shared__ int   se[256];
  __shared__ float red[256];
  int blk = blockIdx.x;
  int n = ((blk & 7) << 11) + (blk >> 3);
  int tid = threadIdx.x;
  {
    ushort4 a = ((const ushort4*)(xl_bf + (size_t)n*1024))[tid];
    ushort4 b = ((const ushort4*)(xr_bf + (size_t)n*1024))[tid];
    float4 c = ((const float4*)we_loop)[tid];
    float4 t = ((const float4*)att)[tid];
    float s = 0.f;
    s += leaky02(bf2f(a.x)+bf2f(b.x)+c.x)*t.x;
    s += leaky02(bf2f(a.y)+bf2f(b.y)+c.y)*t.y;
    s += leaky02(bf2f(a.z)+bf2f(b.z)+c.z)*t.z;
    s += leaky02(bf2f(a.w)+bf2f(b.w)+c.w)*t.w;
    red[tid] = s;
  }
  __syncthreads();
  #pragma unroll
  for (int off=128; off; off>>=1){ if (tid<off) red[tid] += red[tid+off]; __syncthreads(); }
  float sll = red[0];
  __syncthreads();

  int beg = rowptr[n], end = rowptr[n+1], cnt = end - beg;
  float m = -1e30f;
  for (int p = beg+tid; p < end; p += 256) {
    int e = csr[p];
    float lg;
    if (e < N_EDGES) {
      const float4* lp = (const float4*)(logit_part + (size_t)e*8);
      float4 q0 = lp[0], q1 = lp[1];
      lg = q0.x+q0.y+q0.z+q0.w+q1.x+q1.y+q1.z+q1.w;
    } else lg = sll;
    int idx = p - beg;
    if (idx < 256) { se[idx] = e; sl[idx] = lg; }
    m = fmaxf(m, lg);
  }
  red[tid] = m; __syncthreads();
  #pragma unroll
  for (int off=128; off; off>>=1){ if (tid<off) red[tid] = fmaxf(red[tid], red[tid+off]); __syncthreads(); }
  m = red[0];
  __syncthreads();
  float ss = 0.f;
  for (int p = beg+tid; p < end; p += 256) {
    int idx = p - beg;
    ss += expf(sl[idx] - m);
  }
  red[tid] = ss; __syncthreads();
  #pragma unroll
  for (int off=128; off; off>>=1){ if (tid<off) red[tid] += red[tid+off]; __syncthreads(); }
  float inv = 1.f/(red[0] + 1e-16f);
  __syncthreads();
  for (int p = beg+tid; p < end; p += 256) {
    int idx = p - beg;
    float a = expf(sl[idx] - m)*inv;
    alpha[se[idx]] = a;
    sl[idx] = a;
  }
  __syncthreads();
  float4 acc = ((const float4*)bgat)[tid];
  for (int p = 0; p < cnt; p++) {
    float a = sl[p]; int e = se[p];
    int s = (e < N_EDGES) ? ei[e] : (e - N_EDGES);
    ushort4 v = ((const ushort4*)(xl_bf + (size_t)s*1024))[tid];
    acc.x += a*bf2f(v.x); acc.y += a*bf2f(v.y); acc.z += a*bf2f(v.z); acc.w += a*bf2f(v.w);
  }
  ushort4 o; o.x=f2bf(acc.x); o.y=f2bf(acc.y); o.z=f2bf(acc.z); o.w=f2bf(acc.w);
  ((ushort4*)(gat_bf + (size_t)n*1024))[tid] = o;
}

// ---------------- per-graph weighted sums of gat ----------------
__global__ __launch_bounds__(256) void k_nodepool(
    const unsigned short* __restrict__ gat_bf, const int* __restrict__ odeg,
    const int* __restrict__ rowptr,
    float* __restrict__ P_G, float* __restrict__ P_DG, float* __restrict__ P_gat) {
  int b = blockIdx.x, yy = blockIdx.y;
  int nc = yy >> 2, cg = yy & 3;
  int col = cg*256 + threadIdx.x;
  float a1=0.f, a2=0.f, a3=0.f;
  int n0 = b*512 + nc*128;
  for (int i=0;i<128;i++){
    int n = n0 + i;
    float g = bf2f(gat_bf[(size_t)n*1024 + col]);
    float od = (float)odeg[n];
    float dg = (float)(rowptr[n+1]-rowptr[n]);
    a1 += od*g; a2 += dg*g; a3 += g;
  }
  atomicAdd(&P_G[b*1024+col], a1);
  atomicAdd(&P_DG[b*1024+col], a2);
  atomicAdd(&P_gat[b*1024+col], a3);
}

// ---------------- edge pooling ----------------
__global__ __launch_bounds__(256) void k_edgepool(
    const float* __restrict__ ea, const float* __restrict__ We, const float* __restrict__ be,
    const float* __restrict__ alpha, float* __restrict__ P_S, float* __restrict__ pe) {
  __shared__ float sea[640];
  __shared__ float sal[128];
  int b = blockIdx.x, chy = blockIdx.y, tid = threadIdx.x;
  int mode = (chy < 20) ? 0 : 1;
  int ch = (chy < 20) ? chy : (chy - 20);
  int c1 = tid, c2 = tid + 256;
  bool v2 = (c2 < 511);
  float w1[5], w2[5]={0,0,0,0,0}, b1v, b2v=0.f;
  #pragma unroll
  for (int q=0;q<5;q++) w1[q] = We[c1*5+q];
  b1v = be[c1];
  if (v2) {
    #pragma unroll
    for (int q=0;q<5;q++) w2[q] = We[c2*5+q];
    b2v = be[c2];
  }
  int base = (mode == 0)
    ? ((ch < 16) ? (b*2048 + ch*128) : (N_EDGES + b*512 + (ch-16)*128))
    : (b*2560 + ch*128);
  for (int i=tid;i<640;i+=256){
    int r = base + i/5;
    sea[i] = (r < N_EDGES) ? ea[(size_t)r*5 + (i%5)] : 1.0f;
  }
  for (int i=tid;i<128;i+=256) sal[i] = alpha[base + i];
  __syncthreads();
  float acc1 = 0.f, acc2 = 0.f;
  for (int rr=0; rr<128; rr++) {
    const float* er = &sea[rr*5];
    acc1 += leaky01(b1v + er[0]*w1[0]+er[1]*w1[1]+er[2]*w1[2]+er[3]*w1[3]+er[4]*w1[4]);
    if (v2) acc2 += leaky01(b2v + er[0]*w2[0]+er[1]*w2[1]+er[2]*w2[2]+er[3]*w2[3]+er[4]*w2[4]);
    else    acc2 += sal[rr];
  }
  if (mode == 0) {
    atomicAdd(&P_S[b*512+c1], acc1);
    atomicAdd(&P_S[b*512+c2], acc2);
  } else {
    const float sc = 1.f/2560.f;
    atomicAdd(&pe[b*512+c1], acc1*sc);
    atomicAdd(&pe[b*512+c2], acc2*sc);
  }
}

// ---------------- pn via tiny fused GEMMs ----------------
__global__ __launch_bounds__(256) void k_pn(
    const float* __restrict__ P_G, const float* __restrict__ P_DG,
    const float* __restrict__ P_S, const float* __restrict__ P_gat,
    const float* __restrict__ Wm, const float* __restrict__ bm,
    const float* __restrict__ Wmi, const float* __restrict__ bmi,
    const float* __restrict__ Wce, const float* __restrict__ bce,
    float* __restrict__ pn) {
  __shared__ float sPg[1024], sPdg[1024], sPs[512];
  int b = blockIdx.x, col0 = blockIdx.y*64;
  int tid = threadIdx.x, w = tid >> 6, lane = tid & 63;
  for (int i=tid;i<1024;i+=256){ sPg[i]=P_G[b*1024+i]; sPdg[i]=P_DG[b*1024+i]; }
  for (int i=tid;i<512;i+=256) sPs[i]=P_S[b*512+i];
  __syncthreads();
  for (int c=0;c<16;c++){
    int j = col0 + w*16 + c;
    const float* wm  = Wm  + (size_t)j*1024;
    const float* wmi = Wmi + (size_t)j*1024;
    const float* wce = Wce + (size_t)j*512;
    float s = 0.f;
    #pragma unroll 4
    for (int i=0;i<16;i++){ int k = lane + i*64; s += sPg[k]*wm[k] + sPdg[k]*wmi[k]; }
    #pragma unroll 4
    for (int i=0;i<8;i++){ int k = lane + i*64; s += sPs[k]*wce[k]; }
    #pragma unroll
    for (int off=32; off; off>>=1) s += __shfl_down(s, off);
    if (lane == 0) {
      pn[b*1024+j] = (s + P_gat[b*1024+j] + 2560.f*(bm[j]+bmi[j]+bce[j])) * (1.f/512.f);
    }
  }
}

// ---------------- final head ----------------
__global__ __launch_bounds__(256) void k_final(
    const float* __restrict__ pn, const float* __restrict__ pe, const float* __restrict__ yg,
    const float* __restrict__ W1, const float* __restrict__ b1,
    const float* __restrict__ W2, const float* __restrict__ b2,
    float* __restrict__ out) {
  __shared__ float pooled[2048];
  __shared__ float red[256];
  int b = blockIdx.x, tid = threadIdx.x;
  for (int i=tid;i<1024;i+=256) pooled[i]      = pn[b*1024+i];
  for (int i=tid;i<512;i+=256)  pooled[1024+i] = pe[b*512+i];
  for (int i=tid;i<512;i+=256)  pooled[1536+i] = yg[b*512+i];
  __syncthreads();
  const float4* w4 = (const float4*)(W1 + (size_t)tid*2048);
  const float4* p4 = (const float4*)pooled;
  float s = b1[tid];
  for (int k=0;k<512;k++){
    float4 w = w4[k]; float4 p = p4[k];
    s += w.x*p.x + w.y*p.y + w.z*p.z + w.w*p.w;
  }
  s = leaky01(s);
  red[tid] = s * W2[tid];
  __syncthreads();
  for (int off=128; off; off>>=1){
    if (tid < off) red[tid] += red[tid+off];
    __syncthreads();
  }
  if (tid == 0){
    float o = red[0] + b2[0];
    out[b] = 1.f/(1.f+expf(-o));
  }
}

// ---------------- launcher ----------------
extern "C" void kernel_launch(void* const* d_in, const int* in_sizes, int n_in,
                              void* d_out, int out_size, void* d_ws, size_t ws_size,
                              hipStream_t stream) {
  const float* x   = (const float*)d_in[0];
  const int*   ei  = (const int*)  d_in[1];
  const float* ea  = (const float*)d_in[2];
  const float* y   = (const float*)d_in[3];
  const float* Wn  = (const float*)d_in[5];
  const float* bn  = (const float*)d_in[6];
  const float* We  = (const float*)d_in[7];
  const float* be  = (const float*)d_in[8];
  const float* Wg  = (const float*)d_in[9];
  const float* bg  = (const float*)d_in[10];
  const float* Wl  = (const float*)d_in[11];
  const float* bl  = (const float*)d_in[12];
  const float* Wr  = (const float*)d_in[13];
  const float* br  = (const float*)d_in[14];
  const float* Wge = (const float*)d_in[15];
  const float* att = (const float*)d_in[16];
  const float* bgat= (const float*)d_in[17];
  const float* Wm  = (const float*)d_in[18];
  const float* bm  = (const float*)d_in[19];
  const float* Wmi = (const float*)d_in[20];
  const float* bmi = (const float*)d_in[21];
  const float* Wce = (const float*)d_in[22];
  const float* bce = (const float*)d_in[23];
  const float* W1  = (const float*)d_in[24];
  const float* b1  = (const float*)d_in[25];
  const float* W2  = (const float*)d_in[26];
  const float* b2  = (const float*)d_in[27];
  float* out = (float*)d_out;

  char* ws = (char*)d_ws;
  unsigned short* xl_bf  = (unsigned short*)(ws + OFF_XL);
  unsigned short* xr_bf  = (unsigned short*)(ws + OFF_XR);
  unsigned short* gat_bf = (unsigned short*)(ws + OFF_XR);   // alias
  unsigned short* E_bf   = (unsigned short*)(ws + OFF_EBF);
  unsigned short* h_bf   = (unsigned short*)(ws + OFF_HBF);
  unsigned short* Wcat   = (unsigned short*)(ws + OFF_WCAT);
  unsigned short* Wge_p  = (unsigned short*)(ws + OFF_WGEP);
  float* lpart  = (float*)(ws + OFF_LPART);
  float* zone   = (float*)(ws + OFF_DEG);
  int*   deg    = (int*)  (ws + OFF_DEG);
  int*   odeg   = (int*)  (ws + OFF_ODEG);
  int*   cursor = (int*)  (ws + OFF_CURS);
  float* P_G    = (float*)(ws + OFF_PG);
  float* P_DG   = (float*)(ws + OFF_PDG);
  float* P_gat  = (float*)(ws + OFF_PGAT);
  float* P_S    = (float*)(ws + OFF_PS);
  float* pe     = (float*)(ws + OFF_PE);
  int*   rowptr = (int*)  (ws + OFF_ROWP);
  int*   csr    = (int*)  (ws + OFF_CSR);
  float* alpha  = (float*)(ws + OFF_ALPHA);
  float* we_loop= (float*)(ws + OFF_WLOOP);
  float* yg     = (float*)(ws + OFF_YG);
  float* pn     = (float*)(ws + OFF_PN);

  k_prep0<<<dim3(4340), dim3(256), 0, stream>>>(x, Wn, bn, Wl, Wr, Wge, y, Wg, bg, We, be,
                                                zone, h_bf, Wcat, Wge_p, yg, we_loop);
  k_gemm_xlxr<<<dim3(2048), dim3(256), 0, stream>>>(h_bf, Wcat, bl, br, xl_bf, xr_bf);
  k_prep_e<<<dim3(16384), dim3(256), 0, stream>>>(ea, We, be, E_bf);
  k_mfma_we<<<dim3(4096), dim3(256), 0, stream>>>(E_bf, Wge_p, ei, xl_bf, xr_bf, att, lpart);
  k_deg<<<dim3(320), dim3(256), 0, stream>>>(ei, deg, odeg);
  k_scan<<<dim3(1), dim3(1024), 0, stream>>>(deg, rowptr);
  k_fill_csr<<<dim3(320), dim3(256), 0, stream>>>(ei, rowptr, cursor, csr);
  k_softmax_gat<<<dim3(16384), dim3(256), 0, stream>>>(ei, rowptr, csr, lpart, xl_bf, xr_bf,
                                                       we_loop, att, bgat, alpha, gat_bf);
  k_nodepool<<<dim3(32,16), dim3(256), 0, stream>>>(gat_bf, odeg, rowptr, P_G, P_DG, P_gat);
  k_edgepool<<<dim3(32,40), dim3(256), 0, stream>>>(ea, We, be, alpha, P_S, pe);
  k_pn<<<dim3(32,16), dim3(256), 0, stream>>>(P_G, P_DG, P_S, P_gat, Wm, bm, Wmi, bmi, Wce, bce, pn);
  k_final<<<dim3(32), dim3(256), 0, stream>>>(pn, pe, yg, W1, b1, W2, b2, out);
}

// Round 9
// 651.634 us; speedup vs baseline: 1.1261x; 1.1261x over previous
//
#include <hip/hip_runtime.h>
#include <cstdint>
#include <cstddef>

#define N_NODES 16384
#define N_EDGES 65536
#define ETOT    81920
#define B_GR    32

typedef __attribute__((ext_vector_type(8))) short bf16x8;
typedef __attribute__((ext_vector_type(4))) float f32x4;

// ---------------- workspace layout (bytes), peak 138,285,056 ----------------
static constexpr size_t OFF_XL    = 0;              // 33,554,432
static constexpr size_t OFF_XR    = 33554432ULL;    // 33,554,432 (gat_bf aliases)
static constexpr size_t OFF_EBF   = 67108864ULL;    // 67,108,864  E_bf
static constexpr size_t OFF_HBF   = 67108864ULL;    //   alias: h_bf (dead after xlxr GEMM)
static constexpr size_t OFF_WCAT  = 83886080ULL;    //   alias: Wcat (dead after xlxr GEMM)
static constexpr size_t OFF_ROWP  = 67108864ULL;    //   alias: rowptr (after k_mfma_we)
static constexpr size_t OFF_CSR   = 67174656ULL;    //   alias
static constexpr size_t OFF_ALPHA = 67502336ULL;    //   alias
static constexpr size_t OFF_WGEP  = 134217728ULL;   // 1,048,576
static constexpr size_t OFF_LPART = 135266304ULL;   // 2,097,152  logit_part [65536x8 f32]
// ---- zero zone (720,896 B) ----
static constexpr size_t OFF_DEG   = 137363456ULL;
static constexpr size_t OFF_ODEG  = 137428992ULL;
static constexpr size_t OFF_CURS  = 137494528ULL;
static constexpr size_t OFF_PG    = 137560064ULL;
static constexpr size_t OFF_PDG   = 137691136ULL;
static constexpr size_t OFF_PGAT  = 137822208ULL;
static constexpr size_t OFF_PS    = 137953280ULL;
static constexpr size_t OFF_PE    = 138018816ULL;
// ---- end zero zone ----
static constexpr size_t OFF_WLOOP = 138084352ULL;
static constexpr size_t OFF_YG    = 138088448ULL;
static constexpr size_t OFF_PN    = 138153984ULL;
// end = 138,285,056

__device__ __forceinline__ float leaky01(float v){ return v >= 0.f ? v : 0.01f*v; }
__device__ __forceinline__ float leaky02(float v){ return v >= 0.f ? v : 0.2f*v; }
__device__ __forceinline__ unsigned short f2bf(float f){
  union { float f; unsigned u; } v; v.f = f;
  unsigned r = v.u + 0x7FFFu + ((v.u >> 16) & 1u);
  return (unsigned short)(r >> 16);
}
__device__ __forceinline__ float bf2f(unsigned short h){
  union { unsigned u; float f; } v; v.u = ((unsigned)h) << 16;
  return v.f;
}

// ---------------- merged prep ----------------
__global__ __launch_bounds__(256) void k_prep0(
    const float* __restrict__ x, const float* __restrict__ Wn, const float* __restrict__ bn,
    const float* __restrict__ Wl, const float* __restrict__ Wr,
    const float* __restrict__ Wge, const float* __restrict__ y,
    const float* __restrict__ Wg, const float* __restrict__ bg,
    const float* __restrict__ We, const float* __restrict__ be,
    float* __restrict__ zone, unsigned short* __restrict__ h_bf,
    unsigned short* __restrict__ Wcat, unsigned short* __restrict__ Wge_p,
    float* __restrict__ yg, float* __restrict__ we_loop) {
  __shared__ float e_lds[512];
  int bx = blockIdx.x, tid = threadIdx.x;
  if (bx < 176) {
    ((float4*)zone)[bx*256 + tid] = (float4){0.f,0.f,0.f,0.f};
  } else if (bx < 1200) {               // h_bf
    int gid = (bx-176)*256 + tid;
    int base = gid*8;
    int n = base >> 9, j = base & 511;
    float xv = x[n];
    float4 w0 = *(const float4*)(Wn + j);
    float4 w1 = *(const float4*)(Wn + j + 4);
    float4 b0 = *(const float4*)(bn + j);
    float4 b1 = *(const float4*)(bn + j + 4);
    unsigned short o[8];
    o[0]=f2bf(leaky01(xv*w0.x+b0.x)); o[1]=f2bf(leaky01(xv*w0.y+b0.y));
    o[2]=f2bf(leaky01(xv*w0.z+b0.z)); o[3]=f2bf(leaky01(xv*w0.w+b0.w));
    o[4]=f2bf(leaky01(xv*w1.x+b1.x)); o[5]=f2bf(leaky01(xv*w1.y+b1.y));
    o[6]=f2bf(leaky01(xv*w1.z+b1.z)); o[7]=f2bf(leaky01(xv*w1.w+b1.w));
    ((uint4*)h_bf)[gid] = *(const uint4*)o;
  } else if (bx < 2224) {               // Wcat
    int i = (bx-1200)*256 + tid;
    int base = i*4;
    const float* src = (base < 524288) ? (Wl + base) : (Wr + base - 524288);
    float4 v = *(const float4*)src;
    ushort4 o; o.x=f2bf(v.x); o.y=f2bf(v.y); o.z=f2bf(v.z); o.w=f2bf(v.w);
    ((ushort4*)Wcat)[i] = o;
  } else if (bx < 4272) {               // Wge_p
    int gid = (bx-2224)*256 + tid;
    int j = gid >> 9, k = gid & 511;
    Wge_p[gid] = (k < 511) ? f2bf(Wge[(size_t)j*511 + k]) : (unsigned short)0;
  } else if (bx < 4336) {               // yg
    int gid = (bx-4272)*256 + tid;
    int b = gid >> 9, j = gid & 511;
    float s = bg[j];
    #pragma unroll
    for (int k=0;k<5;k++) s += y[b*5+k]*Wg[j*5+k];
    yg[gid] = leaky01(s);
  } else {                              // we_loop
    for (int c = tid; c < 512; c += 256) {
      float v = 0.f;
      if (c < 511) {
        float s = be[c];
        #pragma unroll
        for (int q=0;q<5;q++) s += We[c*5+q];
        v = leaky01(s);
      }
      e_lds[c] = v;
    }
    __syncthreads();
    int j = (bx-4336)*256 + tid;
    float s = 0.f;
    for (int k=0;k<511;k++) s += e_lds[k]*Wge[(size_t)j*511+k];
    we_loop[j] = s;
  }
}

// ---------------- E_bf prep ----------------
__global__ __launch_bounds__(256) void k_prep_e(
    const float* __restrict__ ea, const float* __restrict__ We, const float* __restrict__ be,
    unsigned short* __restrict__ E_bf) {
  int gid = blockIdx.x*256 + threadIdx.x;
  int e = gid >> 6, cg = gid & 63;
  int c0 = cg*8;
  const float* e5 = ea + (size_t)e*5;
  float a0=e5[0], a1=e5[1], a2=e5[2], a3=e5[3], a4=e5[4];
  unsigned short o[8];
  #pragma unroll
  for (int j=0;j<8;j++) {
    int c = c0 + j;
    float v = 0.f;
    if (c < 511) {
      const float* w = We + c*5;
      float s = be[c] + a0*w[0] + a1*w[1] + a2*w[2] + a3*w[3] + a4*w[4];
      v = leaky01(s);
    }
    o[j] = f2bf(v);
  }
  ((uint4*)E_bf)[gid] = *(const uint4*)o;
}

// ---------------- CSR build ----------------
__global__ void k_deg(const int* __restrict__ ei, int* __restrict__ deg, int* __restrict__ odeg) {
  int i = blockIdx.x*blockDim.x + threadIdx.x;
  int s, d;
  if (i < N_EDGES) { s = ei[i]; d = ei[N_EDGES + i]; }
  else { s = i - N_EDGES; d = s; }
  atomicAdd(&deg[d], 1);
  atomicAdd(&odeg[s], 1);
}

__global__ __launch_bounds__(1024) void k_scan(const int* __restrict__ deg, int* __restrict__ rowptr) {
  __shared__ int sums[1024];
  int t = threadIdx.x;
  int local[16]; int s = 0;
  #pragma unroll
  for (int i=0;i<16;i++){ local[i] = deg[t*16+i]; s += local[i]; }
  sums[t] = s; __syncthreads();
  for (int off=1; off<1024; off<<=1) {
    int v = (t >= off) ? sums[t-off] : 0;
    __syncthreads();
    sums[t] += v;
    __syncthreads();
  }
  int run = (t==0) ? 0 : sums[t-1];
  if (t==0) rowptr[0] = 0;
  #pragma unroll
  for (int i=0;i<16;i++){ run += local[i]; rowptr[t*16+i+1] = run; }
}

__global__ void k_fill_csr(const int* __restrict__ ei, const int* __restrict__ rowptr,
                           int* __restrict__ cursor, int* __restrict__ csr) {
  int i = blockIdx.x*blockDim.x + threadIdx.x;
  int d = (i < N_EDGES) ? ei[N_EDGES + i] : (i - N_EDGES);
  int pos = rowptr[d] + atomicAdd(&cursor[d], 1);
  csr[pos] = i;
}

// ================= double-buffered MFMA GEMM core (R7 K-loop) =================

// ---------------- combined xl/xr MFMA GEMM ----------------
__global__ __launch_bounds__(256) void k_gemm_xlxr(
    const unsigned short* __restrict__ h_bf, const unsigned short* __restrict__ Wcat,
    const float* __restrict__ bl, const float* __restrict__ br,
    unsigned short* __restrict__ xl_bf, unsigned short* __restrict__ xr_bf) {
  __shared__ unsigned short As[2][4096];
  __shared__ unsigned short Bs[2][4096];
  int blk = blockIdx.x;
  int xcd = blk & 7, slot = blk >> 3;
  int bx = xcd*16 + (slot >> 4), by = slot & 15;
  int row0 = bx*128, col0 = by*128;
  int tid = threadIdx.x;
  int w = tid >> 6, lane = tid & 63;
  int wm = w >> 1, wn = w & 1;
  int quad = lane >> 4, l16 = lane & 15;
  int ldoff = w*512 + lane*8;
  const unsigned short* gA = h_bf + (size_t)(row0 + w*16 + l16)*512 + quad*8;
  const unsigned short* gB = Wcat + (size_t)(col0 + w*16 + l16)*512 + quad*8;
  f32x4 acc[4][4];
  #pragma unroll
  for (int i=0;i<4;i++)
    #pragma unroll
    for (int j=0;j<4;j++) acc[i][j] = (f32x4){0.f,0.f,0.f,0.f};

  {
    uint4 a0 = *(const uint4*)(gA);
    uint4 a1 = *(const uint4*)(gA + 32768);
    uint4 b0 = *(const uint4*)(gB);
    uint4 b1 = *(const uint4*)(gB + 32768);
    *(uint4*)&As[0][ldoff] = a0; *(uint4*)&As[0][2048+ldoff] = a1;
    *(uint4*)&Bs[0][ldoff] = b0; *(uint4*)&Bs[0][2048+ldoff] = b1;
  }
  __syncthreads();
  int cur = 0;
  #pragma unroll 2
  for (int k0 = 32; k0 <= 512; k0 += 32) {
    uint4 na0, na1, nb0, nb1;
    bool more = (k0 < 512);
    if (more) {
      na0 = *(const uint4*)(gA + k0);
      na1 = *(const uint4*)(gA + 32768 + k0);
      nb0 = *(const uint4*)(gB + k0);
      nb1 = *(const uint4*)(gB + 32768 + k0);
    }
    bf16x8 af[4], bfr[4];
    #pragma unroll
    for (int mi=0;mi<4;mi++)
      af[mi] = *(const bf16x8*)&As[cur][(wm*4+mi)*512 + quad*128 + l16*8];
    #pragma unroll
    for (int ni=0;ni<4;ni++)
      bfr[ni] = *(const bf16x8*)&Bs[cur][(wn*4+ni)*512 + quad*128 + l16*8];
    #pragma unroll
    for (int mi=0;mi<4;mi++)
      #pragma unroll
      for (int ni=0;ni<4;ni++)
        acc[mi][ni] = __builtin_amdgcn_mfma_f32_16x16x32_bf16(af[mi], bfr[ni], acc[mi][ni], 0, 0, 0);
    if (more) {
      *(uint4*)&As[cur^1][ldoff] = na0; *(uint4*)&As[cur^1][2048+ldoff] = na1;
      *(uint4*)&Bs[cur^1][ldoff] = nb0; *(uint4*)&Bs[cur^1][2048+ldoff] = nb1;
    }
    __syncthreads();
    cur ^= 1;
  }
  bool isL = (by < 8);
  const float* bias = isL ? bl : br;
  unsigned short* O = isL ? xl_bf : xr_bf;
  int cb = isL ? col0 : (col0 - 1024);
  float bias4[4];
  #pragma unroll
  for (int ni=0;ni<4;ni++) bias4[ni] = bias[cb + wn*64 + ni*16 + l16];
  #pragma unroll
  for (int mi=0;mi<4;mi++)
    #pragma unroll
    for (int ni=0;ni<4;ni++) {
      int col = cb + wn*64 + ni*16 + l16;
      #pragma unroll
      for (int r=0;r<4;r++) {
        int row = row0 + wm*64 + mi*16 + quad*4 + r;
        O[(size_t)row*1024 + col] = f2bf(acc[mi][ni][r] + bias4[ni]);
      }
    }
}

// ---------------- we-GEMM + fused attention logits ----------------
// R7 K-loop (A+B dbuf LDS) + R8 epilogue (acc transpose via LDS union,
// 16B coalesced xl/xr gathers, 4-lane reduce).
__global__ __launch_bounds__(256) void k_mfma_we(
    const unsigned short* __restrict__ E_bf, const unsigned short* __restrict__ Wge_bf,
    const int* __restrict__ ei,
    const unsigned short* __restrict__ xl_bf, const unsigned short* __restrict__ xr_bf,
    const float* __restrict__ att, float* __restrict__ logit_part) {
  __shared__ alignas(16) char smem[33280];   // K-loop: As[2][4096]+Bs[2][4096] (32,768 B); epilogue: accT f32[64][130]
  unsigned short (*As)[4096] = (unsigned short (*)[4096])smem;
  unsigned short (*Bs)[4096] = (unsigned short (*)[4096])(smem + 16384);
  float* accT = (float*)smem;
  int blk = blockIdx.x;
  int xcd = blk & 7, slot = blk >> 3;
  int bx = xcd*64 + (slot >> 3), by = slot & 7;
  int row0 = bx*128, col0 = by*128;
  int tid = threadIdx.x;
  int w = tid >> 6, lane = tid & 63;
  int wm = w >> 1, wn = w & 1;
  int quad = lane >> 4, l16 = lane & 15;
  int ldoff = w*512 + lane*8;
  const unsigned short* gA = E_bf  + (size_t)(row0 + w*16 + l16)*512 + quad*8;
  const unsigned short* gB = Wge_bf + (size_t)(col0 + w*16 + l16)*512 + quad*8;
  f32x4 acc[4][4];
  #pragma unroll
  for (int i=0;i<4;i++)
    #pragma unroll
    for (int j=0;j<4;j++) acc[i][j] = (f32x4){0.f,0.f,0.f,0.f};

  {
    uint4 a0 = *(const uint4*)(gA);
    uint4 a1 = *(const uint4*)(gA + 32768);
    uint4 b0 = *(const uint4*)(gB);
    uint4 b1 = *(const uint4*)(gB + 32768);
    *(uint4*)&As[0][ldoff] = a0; *(uint4*)&As[0][2048+ldoff] = a1;
    *(uint4*)&Bs[0][ldoff] = b0; *(uint4*)&Bs[0][2048+ldoff] = b1;
  }
  __syncthreads();
  int cur = 0;
  #pragma unroll 2
  for (int k0 = 32; k0 <= 512; k0 += 32) {
    uint4 na0, na1, nb0, nb1;
    bool more = (k0 < 512);
    if (more) {
      na0 = *(const uint4*)(gA + k0);
      na1 = *(const uint4*)(gA + 32768 + k0);
      nb0 = *(const uint4*)(gB + k0);
      nb1 = *(const uint4*)(gB + 32768 + k0);
    }
    bf16x8 af[4], bfr[4];
    #pragma unroll
    for (int mi=0;mi<4;mi++)
      af[mi] = *(const bf16x8*)&As[cur][(wm*4+mi)*512 + quad*128 + l16*8];
    #pragma unroll
    for (int ni=0;ni<4;ni++)
      bfr[ni] = *(const bf16x8*)&Bs[cur][(wn*4+ni)*512 + quad*128 + l16*8];
    #pragma unroll
    for (int mi=0;mi<4;mi++)
      #pragma unroll
      for (int ni=0;ni<4;ni++)
        acc[mi][ni] = __builtin_amdgcn_mfma_f32_16x16x32_bf16(af[mi], bfr[ni], acc[mi][ni], 0, 0, 0);
    if (more) {
      *(uint4*)&As[cur^1][ldoff] = na0; *(uint4*)&As[cur^1][2048+ldoff] = na1;
      *(uint4*)&Bs[cur^1][ldoff] = nb0; *(uint4*)&Bs[cur^1][2048+ldoff] = nb1;
    }
    __syncthreads();
    cur ^= 1;
  }
  // ---- epilogue: 2 passes over edge-halves; accT reuses smem (K-loop done) ----
  int e_loc = tid >> 2, cq = tid & 3;
  #pragma unroll
  for (int eh = 0; eh < 2; eh++) {
    if (wm == eh) {
      #pragma unroll
      for (int mi=0;mi<4;mi++)
        #pragma unroll
        for (int ni=0;ni<4;ni++) {
          int colb = wn*64 + ni*16 + l16;
          #pragma unroll
          for (int r=0;r<4;r++)
            accT[(mi*16 + quad*4 + r)*130 + colb] = acc[mi][ni][r];
        }
    }
    __syncthreads();
    int e = row0 + eh*64 + e_loc;
    int s = ei[e], d = ei[N_EDGES + e];
    const uint4* xlp = (const uint4*)(xl_bf + (size_t)s*1024 + col0 + cq*32);
    const uint4* xrp = (const uint4*)(xr_bf + (size_t)d*1024 + col0 + cq*32);
    const float* accrow = accT + e_loc*130 + cq*32;
    const float* attp = att + col0 + cq*32;
    float p = 0.f;
    #pragma unroll
    for (int g=0; g<4; g++) {
      uint4 xa = xlp[g];
      uint4 xb = xrp[g];
      float4 at0 = *(const float4*)(attp + g*8);
      float4 at1 = *(const float4*)(attp + g*8 + 4);
      float4 ac0 = *(const float4*)(accrow + g*8);
      float4 ac1 = *(const float4*)(accrow + g*8 + 4);
      const unsigned short* ua = (const unsigned short*)&xa;
      const unsigned short* ub = (const unsigned short*)&xb;
      float z;
      z = ac0.x + bf2f(ua[0]) + bf2f(ub[0]); z = leaky02(z); p += z*at0.x;
      z = ac0.y + bf2f(ua[1]) + bf2f(ub[1]); z = leaky02(z); p += z*at0.y;
      z = ac0.z + bf2f(ua[2]) + bf2f(ub[2]); z = leaky02(z); p += z*at0.z;
      z = ac0.w + bf2f(ua[3]) + bf2f(ub[3]); z = leaky02(z); p += z*at0.w;
      z = ac1.x + bf2f(ua[4]) + bf2f(ub[4]); z = leaky02(z); p += z*at1.x;
      z = ac1.y + bf2f(ua[5]) + bf2f(ub[5]); z = leaky02(z); p += z*at1.y;
      z = ac1.z + bf2f(ua[6]) + bf2f(ub[6]); z = leaky02(z); p += z*at1.z;
      z = ac1.w + bf2f(ua[7]) + bf2f(ub[7]); z = leaky02(z); p += z*at1.w;
    }
    p += __shfl_down(p, 2, 4);
    p += __shfl_down(p, 1, 4);
    if (cq == 0) logit_part[(size_t)e*8 + by] = p;
    __syncthreads();
  }
}

// ---------------- fused: self-loop logit + softmax + GAT aggregation ----------------
__global__ __launch_bounds__(256) void k_softmax_gat(
    const int* __restrict__ ei, const int* __restrict__ rowptr, const int* __restrict__ csr,
    const float* __restrict__ logit_part,
    const unsigned short* __restrict__ xl_bf, const unsigned short* __restrict__ xr_bf,
    const float* __restrict__ we_loop, const float* __restrict__ att,
    const float* __restrict__ bgat,
    float* __restrict__ alpha, unsigned short* __restrict__ gat_bf) {
  __shared__ float sl[256];
  __shared__ int   se[256];
  __shared__ float red[256];
  int blk = blockIdx.x;
  int n = ((blk & 7) << 11) + (blk >> 3);
  int tid = threadIdx.x;
  {
    ushort4 a = ((const ushort4*)(xl_bf + (size_t)n*1024))[tid];
    ushort4 b = ((const ushort4*)(xr_bf + (size_t)n*1024))[tid];
    float4 c = ((const float4*)we_loop)[tid];
    float4 t = ((const float4*)att)[tid];
    float s = 0.f;
    s += leaky02(bf2f(a.x)+bf2f(b.x)+c.x)*t.x;
    s += leaky02(bf2f(a.y)+bf2f(b.y)+c.y)*t.y;
    s += leaky02(bf2f(a.z)+bf2f(b.z)+c.z)*t.z;
    s += leaky02(bf2f(a.w)+bf2f(b.w)+c.w)*t.w;
    red[tid] = s;
  }
  __syncthreads();
  #pragma unroll
  for (int off=128; off; off>>=1){ if (tid<off) red[tid] += red[tid+off]; __syncthreads(); }
  float sll = red[0];
  __syncthreads();

  int beg = rowptr[n], end = rowptr[n+1], cnt = end - beg;
  float m = -1e30f;
  for (int p = beg+tid; p < end; p += 256) {
    int e = csr[p];
    float lg;
    if (e < N_EDGES) {
      const float4* lp = (const float4*)(logit_part + (size_t)e*8);
      float4 q0 = lp[0], q1 = lp[1];
      lg = q0.x+q0.y+q0.z+q0.w+q1.x+q1.y+q1.z+q1.w;
    } else lg = sll;
    int idx = p - beg;
    if (idx < 256) { se[idx] = e; sl[idx] = lg; }
    m = fmaxf(m, lg);
  }
  red[tid] = m; __syncthreads();
  #pragma unroll
  for (int off=128; off; off>>=1){ if (tid<off) red[tid] = fmaxf(red[tid], red[tid+off]); __syncthreads(); }
  m = red[0];
  __syncthreads();
  float ss = 0.f;
  for (int p = beg+tid; p < end; p += 256) {
    int idx = p - beg;
    ss += expf(sl[idx] - m);
  }
  red[tid] = ss; __syncthreads();
  #pragma unroll
  for (int off=128; off; off>>=1){ if (tid<off) red[tid] += red[tid+off]; __syncthreads(); }
  float inv = 1.f/(red[0] + 1e-16f);
  __syncthreads();
  for (int p = beg+tid; p < end; p += 256) {
    int idx = p - beg;
    float a = expf(sl[idx] - m)*inv;
    alpha[se[idx]] = a;
    sl[idx] = a;
  }
  __syncthreads();
  float4 acc = ((const float4*)bgat)[tid];
  for (int p = 0; p < cnt; p++) {
    float a = sl[p]; int e = se[p];
    int s = (e < N_EDGES) ? ei[e] : (e - N_EDGES);
    ushort4 v = ((const ushort4*)(xl_bf + (size_t)s*1024))[tid];
    acc.x += a*bf2f(v.x); acc.y += a*bf2f(v.y); acc.z += a*bf2f(v.z); acc.w += a*bf2f(v.w);
  }
  ushort4 o; o.x=f2bf(acc.x); o.y=f2bf(acc.y); o.z=f2bf(acc.z); o.w=f2bf(acc.w);
  ((ushort4*)(gat_bf + (size_t)n*1024))[tid] = o;
}

// ---------------- per-graph weighted sums of gat ----------------
__global__ __launch_bounds__(256) void k_nodepool(
    const unsigned short* __restrict__ gat_bf, const int* __restrict__ odeg,
    const int* __restrict__ rowptr,
    float* __restrict__ P_G, float* __restrict__ P_DG, float* __restrict__ P_gat) {
  int b = blockIdx.x, yy = blockIdx.y;
  int nc = yy >> 2, cg = yy & 3;
  int col = cg*256 + threadIdx.x;
  float a1=0.f, a2=0.f, a3=0.f;
  int n0 = b*512 + nc*128;
  for (int i=0;i<128;i++){
    int n = n0 + i;
    float g = bf2f(gat_bf[(size_t)n*1024 + col]);
    float od = (float)odeg[n];
    float dg = (float)(rowptr[n+1]-rowptr[n]);
    a1 += od*g; a2 += dg*g; a3 += g;
  }
  atomicAdd(&P_G[b*1024+col], a1);
  atomicAdd(&P_DG[b*1024+col], a2);
  atomicAdd(&P_gat[b*1024+col], a3);
}

// ---------------- edge pooling ----------------
__global__ __launch_bounds__(256) void k_edgepool(
    const float* __restrict__ ea, const float* __restrict__ We, const float* __restrict__ be,
    const float* __restrict__ alpha, float* __restrict__ P_S, float* __restrict__ pe) {
  __shared__ float sea[640];
  __shared__ float sal[128];
  int b = blockIdx.x, chy = blockIdx.y, tid = threadIdx.x;
  int mode = (chy < 20) ? 0 : 1;
  int ch = (chy < 20) ? chy : (chy - 20);
  int c1 = tid, c2 = tid + 256;
  bool v2 = (c2 < 511);
  float w1[5], w2[5]={0,0,0,0,0}, b1v, b2v=0.f;
  #pragma unroll
  for (int q=0;q<5;q++) w1[q] = We[c1*5+q];
  b1v = be[c1];
  if (v2) {
    #pragma unroll
    for (int q=0;q<5;q++) w2[q] = We[c2*5+q];
    b2v = be[c2];
  }
  int base = (mode == 0)
    ? ((ch < 16) ? (b*2048 + ch*128) : (N_EDGES + b*512 + (ch-16)*128))
    : (b*2560 + ch*128);
  for (int i=tid;i<640;i+=256){
    int r = base + i/5;
    sea[i] = (r < N_EDGES) ? ea[(size_t)r*5 + (i%5)] : 1.0f;
  }
  for (int i=tid;i<128;i+=256) sal[i] = alpha[base + i];
  __syncthreads();
  float acc1 = 0.f, acc2 = 0.f;
  for (int rr=0; rr<128; rr++) {
    const float* er = &sea[rr*5];
    acc1 += leaky01(b1v + er[0]*w1[0]+er[1]*w1[1]+er[2]*w1[2]+er[3]*w1[3]+er[4]*w1[4]);
    if (v2) acc2 += leaky01(b2v + er[0]*w2[0]+er[1]*w2[1]+er[2]*w2[2]+er[3]*w2[3]+er[4]*w2[4]);
    else    acc2 += sal[rr];
  }
  if (mode == 0) {
    atomicAdd(&P_S[b*512+c1], acc1);
    atomicAdd(&P_S[b*512+c2], acc2);
  } else {
    const float sc = 1.f/2560.f;
    atomicAdd(&pe[b*512+c1], acc1*sc);
    atomicAdd(&pe[b*512+c2], acc2*sc);
  }
}

// ---------------- pn via tiny fused GEMMs ----------------
__global__ __launch_bounds__(256) void k_pn(
    const float* __restrict__ P_G, const float* __restrict__ P_DG,
    const float* __restrict__ P_S, const float* __restrict__ P_gat,
    const float* __restrict__ Wm, const float* __restrict__ bm,
    const float* __restrict__ Wmi, const float* __restrict__ bmi,
    const float* __restrict__ Wce, const float* __restrict__ bce,
    float* __restrict__ pn) {
  __shared__ float sPg[1024], sPdg[1024], sPs[512];
  int b = blockIdx.x, col0 = blockIdx.y*64;
  int tid = threadIdx.x, w = tid >> 6, lane = tid & 63;
  for (int i=tid;i<1024;i+=256){ sPg[i]=P_G[b*1024+i]; sPdg[i]=P_DG[b*1024+i]; }
  for (int i=tid;i<512;i+=256) sPs[i]=P_S[b*512+i];
  __syncthreads();
  for (int c=0;c<16;c++){
    int j = col0 + w*16 + c;
    const float* wm  = Wm  + (size_t)j*1024;
    const float* wmi = Wmi + (size_t)j*1024;
    const float* wce = Wce + (size_t)j*512;
    float s = 0.f;
    #pragma unroll 4
    for (int i=0;i<16;i++){ int k = lane + i*64; s += sPg[k]*wm[k] + sPdg[k]*wmi[k]; }
    #pragma unroll 4
    for (int i=0;i<8;i++){ int k = lane + i*64; s += sPs[k]*wce[k]; }
    #pragma unroll
    for (int off=32; off; off>>=1) s += __shfl_down(s, off);
    if (lane == 0) {
      pn[b*1024+j] = (s + P_gat[b*1024+j] + 2560.f*(bm[j]+bmi[j]+bce[j])) * (1.f/512.f);
    }
  }
}

// ---------------- final head ----------------
__global__ __launch_bounds__(256) void k_final(
    const float* __restrict__ pn, const float* __restrict__ pe, const float* __restrict__ yg,
    const float* __restrict__ W1, const float* __restrict__ b1,
    const float* __restrict__ W2, const float* __restrict__ b2,
    float* __restrict__ out) {
  __shared__ float pooled[2048];
  __shared__ float red[256];
  int b = blockIdx.x, tid = threadIdx.x;
  for (int i=tid;i<1024;i+=256) pooled[i]      = pn[b*1024+i];
  for (int i=tid;i<512;i+=256)  pooled[1024+i] = pe[b*512+i];
  for (int i=tid;i<512;i+=256)  pooled[1536+i] = yg[b*512+i];
  __syncthreads();
  const float4* w4 = (const float4*)(W1 + (size_t)tid*2048);
  const float4* p4 = (const float4*)pooled;
  float s = b1[tid];
  for (int k=0;k<512;k++){
    float4 w = w4[k]; float4 p = p4[k];
    s += w.x*p.x + w.y*p.y + w.z*p.z + w.w*p.w;
  }
  s = leaky01(s);
  red[tid] = s * W2[tid];
  __syncthreads();
  for (int off=128; off; off>>=1){
    if (tid < off) red[tid] += red[tid+off];
    __syncthreads();
  }
  if (tid == 0){
    float o = red[0] + b2[0];
    out[b] = 1.f/(1.f+expf(-o));
  }
}

// ---------------- launcher ----------------
extern "C" void kernel_launch(void* const* d_in, const int* in_sizes, int n_in,
                              void* d_out, int out_size, void* d_ws, size_t ws_size,
                              hipStream_t stream) {
  const float* x   = (const float*)d_in[0];
  const int*   ei  = (const int*)  d_in[1];
  const float* ea  = (const float*)d_in[2];
  const float* y   = (const float*)d_in[3];
  const float* Wn  = (const float*)d_in[5];
  const float* bn  = (const float*)d_in[6];
  const float* We  = (const float*)d_in[7];
  const float* be  = (const float*)d_in[8];
  const float* Wg  = (const float*)d_in[9];
  const float* bg  = (const float*)d_in[10];
  const float* Wl  = (const float*)d_in[11];
  const float* bl  = (const float*)d_in[12];
  const float* Wr  = (const float*)d_in[13];
  const float* br  = (const float*)d_in[14];
  const float* Wge = (const float*)d_in[15];
  const float* att = (const float*)d_in[16];
  const float* bgat= (const float*)d_in[17];
  const float* Wm  = (const float*)d_in[18];
  const float* bm  = (const float*)d_in[19];
  const float* Wmi = (const float*)d_in[20];
  const float* bmi = (const float*)d_in[21];
  const float* Wce = (const float*)d_in[22];
  const float* bce = (const float*)d_in[23];
  const float* W1  = (const float*)d_in[24];
  const float* b1  = (const float*)d_in[25];
  const float* W2  = (const float*)d_in[26];
  const float* b2  = (const float*)d_in[27];
  float* out = (float*)d_out;

  char* ws = (char*)d_ws;
  unsigned short* xl_bf  = (unsigned short*)(ws + OFF_XL);
  unsigned short* xr_bf  = (unsigned short*)(ws + OFF_XR);
  unsigned short* gat_bf = (unsigned short*)(ws + OFF_XR);   // alias
  unsigned short* E_bf   = (unsigned short*)(ws + OFF_EBF);
  unsigned short* h_bf   = (unsigned short*)(ws + OFF_HBF);
  unsigned short* Wcat   = (unsigned short*)(ws + OFF_WCAT);
  unsigned short* Wge_p  = (unsigned short*)(ws + OFF_WGEP);
  float* lpart  = (float*)(ws + OFF_LPART);
  float* zone   = (float*)(ws + OFF_DEG);
  int*   deg    = (int*)  (ws + OFF_DEG);
  int*   odeg   = (int*)  (ws + OFF_ODEG);
  int*   cursor = (int*)  (ws + OFF_CURS);
  float* P_G    = (float*)(ws + OFF_PG);
  float* P_DG   = (float*)(ws + OFF_PDG);
  float* P_gat  = (float*)(ws + OFF_PGAT);
  float* P_S    = (float*)(ws + OFF_PS);
  float* pe     = (float*)(ws + OFF_PE);
  int*   rowptr = (int*)  (ws + OFF_ROWP);
  int*   csr    = (int*)  (ws + OFF_CSR);
  float* alpha  = (float*)(ws + OFF_ALPHA);
  float* we_loop= (float*)(ws + OFF_WLOOP);
  float* yg     = (float*)(ws + OFF_YG);
  float* pn     = (float*)(ws + OFF_PN);

  k_prep0<<<dim3(4340), dim3(256), 0, stream>>>(x, Wn, bn, Wl, Wr, Wge, y, Wg, bg, We, be,
                                                zone, h_bf, Wcat, Wge_p, yg, we_loop);
  k_gemm_xlxr<<<dim3(2048), dim3(256), 0, stream>>>(h_bf, Wcat, bl, br, xl_bf, xr_bf);
  k_prep_e<<<dim3(16384), dim3(256), 0, stream>>>(ea, We, be, E_bf);
  k_mfma_we<<<dim3(4096), dim3(256), 0, stream>>>(E_bf, Wge_p, ei, xl_bf, xr_bf, att, lpart);
  k_deg<<<dim3(320), dim3(256), 0, stream>>>(ei, deg, odeg);
  k_scan<<<dim3(1), dim3(1024), 0, stream>>>(deg, rowptr);
  k_fill_csr<<<dim3(320), dim3(256), 0, stream>>>(ei, rowptr, cursor, csr);
  k_softmax_gat<<<dim3(16384), dim3(256), 0, stream>>>(ei, rowptr, csr, lpart, xl_bf, xr_bf,
                                                       we_loop, att, bgat, alpha, gat_bf);
  k_nodepool<<<dim3(32,16), dim3(256), 0, stream>>>(gat_bf, odeg, rowptr, P_G, P_DG, P_gat);
  k_edgepool<<<dim3(32,40), dim3(256), 0, stream>>>(ea, We, be, alpha, P_S, pe);
  k_pn<<<dim3(32,16), dim3(256), 0, stream>>>(P_G, P_DG, P_S, P_gat, Wm, bm, Wmi, bmi, Wce, bce, pn);
  k_final<<<dim3(32), dim3(256), 0, stream>>>(pn, pe, yg, W1, b1, W2, b2, out);
}

// Round 10
// 631.443 us; speedup vs baseline: 1.1621x; 1.0320x over previous
//
#include <hip/hip_runtime.h>
#include <cstdint>
#include <cstddef>

#define N_NODES 16384
#define N_EDGES 65536
#define ETOT    81920
#define B_GR    32

typedef __attribute__((ext_vector_type(8))) short bf16x8;
typedef __attribute__((ext_vector_type(4))) float f32x4;

// ---------------- workspace layout (bytes), peak 138,285,056 ----------------
static constexpr size_t OFF_XL    = 0;              // 33,554,432
static constexpr size_t OFF_XR    = 33554432ULL;    // 33,554,432 (gat_bf aliases)
static constexpr size_t OFF_EBF   = 67108864ULL;    // 67,108,864  E_bf
static constexpr size_t OFF_HBF   = 67108864ULL;    //   alias: h_bf (dead after xlxr GEMM)
static constexpr size_t OFF_WCAT  = 83886080ULL;    //   alias: Wcat (dead after xlxr GEMM)
static constexpr size_t OFF_ROWP  = 67108864ULL;    //   alias: rowptr (after k_mfma_we)
static constexpr size_t OFF_CSR   = 67174656ULL;    //   alias
static constexpr size_t OFF_ALPHA = 67502336ULL;    //   alias
static constexpr size_t OFF_WGEP  = 134217728ULL;   // 1,048,576
static constexpr size_t OFF_LPART = 135266304ULL;   // 2,097,152  logit_part [65536x8 f32]
// ---- zero zone (720,896 B) ----
static constexpr size_t OFF_DEG   = 137363456ULL;
static constexpr size_t OFF_ODEG  = 137428992ULL;
static constexpr size_t OFF_CURS  = 137494528ULL;
static constexpr size_t OFF_PG    = 137560064ULL;
static constexpr size_t OFF_PDG   = 137691136ULL;
static constexpr size_t OFF_PGAT  = 137822208ULL;
static constexpr size_t OFF_PS    = 137953280ULL;
static constexpr size_t OFF_PE    = 138018816ULL;
// ---- end zero zone ----
static constexpr size_t OFF_WLOOP = 138084352ULL;
static constexpr size_t OFF_YG    = 138088448ULL;
static constexpr size_t OFF_PN    = 138153984ULL;
// end = 138,285,056

__device__ __forceinline__ float leaky01(float v){ return v >= 0.f ? v : 0.01f*v; }
__device__ __forceinline__ float leaky02(float v){ return v >= 0.f ? v : 0.2f*v; }
__device__ __forceinline__ unsigned short f2bf(float f){
  union { float f; unsigned u; } v; v.f = f;
  unsigned r = v.u + 0x7FFFu + ((v.u >> 16) & 1u);
  return (unsigned short)(r >> 16);
}
__device__ __forceinline__ float bf2f(unsigned short h){
  union { unsigned u; float f; } v; v.u = ((unsigned)h) << 16;
  return v.f;
}

// ---------------- merged prep ----------------
__global__ __launch_bounds__(256) void k_prep0(
    const float* __restrict__ x, const float* __restrict__ Wn, const float* __restrict__ bn,
    const float* __restrict__ Wl, const float* __restrict__ Wr,
    const float* __restrict__ Wge, const float* __restrict__ y,
    const float* __restrict__ Wg, const float* __restrict__ bg,
    const float* __restrict__ We, const float* __restrict__ be,
    float* __restrict__ zone, unsigned short* __restrict__ h_bf,
    unsigned short* __restrict__ Wcat, unsigned short* __restrict__ Wge_p,
    float* __restrict__ yg, float* __restrict__ we_loop) {
  __shared__ float e_lds[512];
  int bx = blockIdx.x, tid = threadIdx.x;
  if (bx < 176) {
    ((float4*)zone)[bx*256 + tid] = (float4){0.f,0.f,0.f,0.f};
  } else if (bx < 1200) {               // h_bf
    int gid = (bx-176)*256 + tid;
    int base = gid*8;
    int n = base >> 9, j = base & 511;
    float xv = x[n];
    float4 w0 = *(const float4*)(Wn + j);
    float4 w1 = *(const float4*)(Wn + j + 4);
    float4 b0 = *(const float4*)(bn + j);
    float4 b1 = *(const float4*)(bn + j + 4);
    unsigned short o[8];
    o[0]=f2bf(leaky01(xv*w0.x+b0.x)); o[1]=f2bf(leaky01(xv*w0.y+b0.y));
    o[2]=f2bf(leaky01(xv*w0.z+b0.z)); o[3]=f2bf(leaky01(xv*w0.w+b0.w));
    o[4]=f2bf(leaky01(xv*w1.x+b1.x)); o[5]=f2bf(leaky01(xv*w1.y+b1.y));
    o[6]=f2bf(leaky01(xv*w1.z+b1.z)); o[7]=f2bf(leaky01(xv*w1.w+b1.w));
    ((uint4*)h_bf)[gid] = *(const uint4*)o;
  } else if (bx < 2224) {               // Wcat
    int i = (bx-1200)*256 + tid;
    int base = i*4;
    const float* src = (base < 524288) ? (Wl + base) : (Wr + base - 524288);
    float4 v = *(const float4*)src;
    ushort4 o; o.x=f2bf(v.x); o.y=f2bf(v.y); o.z=f2bf(v.z); o.w=f2bf(v.w);
    ((ushort4*)Wcat)[i] = o;
  } else if (bx < 4272) {               // Wge_p
    int gid = (bx-2224)*256 + tid;
    int j = gid >> 9, k = gid & 511;
    Wge_p[gid] = (k < 511) ? f2bf(Wge[(size_t)j*511 + k]) : (unsigned short)0;
  } else if (bx < 4336) {               // yg
    int gid = (bx-4272)*256 + tid;
    int b = gid >> 9, j = gid & 511;
    float s = bg[j];
    #pragma unroll
    for (int k=0;k<5;k++) s += y[b*5+k]*Wg[j*5+k];
    yg[gid] = leaky01(s);
  } else {                              // we_loop
    for (int c = tid; c < 512; c += 256) {
      float v = 0.f;
      if (c < 511) {
        float s = be[c];
        #pragma unroll
        for (int q=0;q<5;q++) s += We[c*5+q];
        v = leaky01(s);
      }
      e_lds[c] = v;
    }
    __syncthreads();
    int j = (bx-4336)*256 + tid;
    float s = 0.f;
    for (int k=0;k<511;k++) s += e_lds[k]*Wge[(size_t)j*511+k];
    we_loop[j] = s;
  }
}

// ---------------- E_bf prep + degree counts (merged) ----------------
// grid 16704: blocks 0..16383 write E_bf; 16384..16703 do degree atomics
__global__ __launch_bounds__(256) void k_prep_e(
    const float* __restrict__ ea, const float* __restrict__ We, const float* __restrict__ be,
    unsigned short* __restrict__ E_bf,
    const int* __restrict__ ei, int* __restrict__ deg, int* __restrict__ odeg) {
  int blk = blockIdx.x;
  if (blk < 16384) {
    int gid = blk*256 + threadIdx.x;
    int e = gid >> 6, cg = gid & 63;
    int c0 = cg*8;
    const float* e5 = ea + (size_t)e*5;
    float a0=e5[0], a1=e5[1], a2=e5[2], a3=e5[3], a4=e5[4];
    unsigned short o[8];
    #pragma unroll
    for (int j=0;j<8;j++) {
      int c = c0 + j;
      float v = 0.f;
      if (c < 511) {
        const float* w = We + c*5;
        float s = be[c] + a0*w[0] + a1*w[1] + a2*w[2] + a3*w[3] + a4*w[4];
        v = leaky01(s);
      }
      o[j] = f2bf(v);
    }
    ((uint4*)E_bf)[gid] = *(const uint4*)o;
  } else {
    int i = (blk-16384)*256 + threadIdx.x;  // < ETOT
    int s, d;
    if (i < N_EDGES) { s = ei[i]; d = ei[N_EDGES + i]; }
    else { s = i - N_EDGES; d = s; }
    atomicAdd(&deg[d], 1);
    atomicAdd(&odeg[s], 1);
  }
}

// ---------------- CSR build ----------------
__global__ __launch_bounds__(1024) void k_scan(const int* __restrict__ deg, int* __restrict__ rowptr) {
  __shared__ int sums[1024];
  int t = threadIdx.x;
  int local[16]; int s = 0;
  #pragma unroll
  for (int i=0;i<16;i++){ local[i] = deg[t*16+i]; s += local[i]; }
  sums[t] = s; __syncthreads();
  for (int off=1; off<1024; off<<=1) {
    int v = (t >= off) ? sums[t-off] : 0;
    __syncthreads();
    sums[t] += v;
    __syncthreads();
  }
  int run = (t==0) ? 0 : sums[t-1];
  if (t==0) rowptr[0] = 0;
  #pragma unroll
  for (int i=0;i<16;i++){ run += local[i]; rowptr[t*16+i+1] = run; }
}

__global__ void k_fill_csr(const int* __restrict__ ei, const int* __restrict__ rowptr,
                           int* __restrict__ cursor, int* __restrict__ csr) {
  int i = blockIdx.x*blockDim.x + threadIdx.x;
  int d = (i < N_EDGES) ? ei[N_EDGES + i] : (i - N_EDGES);
  int pos = rowptr[d] + atomicAdd(&cursor[d], 1);
  csr[pos] = i;
}

// ================= double-buffered MFMA GEMM core (R7, proven) =================

// ---------------- combined xl/xr MFMA GEMM ----------------
__global__ __launch_bounds__(256) void k_gemm_xlxr(
    const unsigned short* __restrict__ h_bf, const unsigned short* __restrict__ Wcat,
    const float* __restrict__ bl, const float* __restrict__ br,
    unsigned short* __restrict__ xl_bf, unsigned short* __restrict__ xr_bf) {
  __shared__ unsigned short As[2][4096];
  __shared__ unsigned short Bs[2][4096];
  int blk = blockIdx.x;
  int xcd = blk & 7, slot = blk >> 3;
  int bx = xcd*16 + (slot >> 4), by = slot & 15;
  int row0 = bx*128, col0 = by*128;
  int tid = threadIdx.x;
  int w = tid >> 6, lane = tid & 63;
  int wm = w >> 1, wn = w & 1;
  int quad = lane >> 4, l16 = lane & 15;
  int ldoff = w*512 + lane*8;
  const unsigned short* gA = h_bf + (size_t)(row0 + w*16 + l16)*512 + quad*8;
  const unsigned short* gB = Wcat + (size_t)(col0 + w*16 + l16)*512 + quad*8;
  f32x4 acc[4][4];
  #pragma unroll
  for (int i=0;i<4;i++)
    #pragma unroll
    for (int j=0;j<4;j++) acc[i][j] = (f32x4){0.f,0.f,0.f,0.f};

  {
    uint4 a0 = *(const uint4*)(gA);
    uint4 a1 = *(const uint4*)(gA + 32768);
    uint4 b0 = *(const uint4*)(gB);
    uint4 b1 = *(const uint4*)(gB + 32768);
    *(uint4*)&As[0][ldoff] = a0; *(uint4*)&As[0][2048+ldoff] = a1;
    *(uint4*)&Bs[0][ldoff] = b0; *(uint4*)&Bs[0][2048+ldoff] = b1;
  }
  __syncthreads();
  int cur = 0;
  #pragma unroll 2
  for (int k0 = 32; k0 <= 512; k0 += 32) {
    uint4 na0, na1, nb0, nb1;
    bool more = (k0 < 512);
    if (more) {
      na0 = *(const uint4*)(gA + k0);
      na1 = *(const uint4*)(gA + 32768 + k0);
      nb0 = *(const uint4*)(gB + k0);
      nb1 = *(const uint4*)(gB + 32768 + k0);
    }
    bf16x8 af[4], bfr[4];
    #pragma unroll
    for (int mi=0;mi<4;mi++)
      af[mi] = *(const bf16x8*)&As[cur][(wm*4+mi)*512 + quad*128 + l16*8];
    #pragma unroll
    for (int ni=0;ni<4;ni++)
      bfr[ni] = *(const bf16x8*)&Bs[cur][(wn*4+ni)*512 + quad*128 + l16*8];
    #pragma unroll
    for (int mi=0;mi<4;mi++)
      #pragma unroll
      for (int ni=0;ni<4;ni++)
        acc[mi][ni] = __builtin_amdgcn_mfma_f32_16x16x32_bf16(af[mi], bfr[ni], acc[mi][ni], 0, 0, 0);
    if (more) {
      *(uint4*)&As[cur^1][ldoff] = na0; *(uint4*)&As[cur^1][2048+ldoff] = na1;
      *(uint4*)&Bs[cur^1][ldoff] = nb0; *(uint4*)&Bs[cur^1][2048+ldoff] = nb1;
    }
    __syncthreads();
    cur ^= 1;
  }
  bool isL = (by < 8);
  const float* bias = isL ? bl : br;
  unsigned short* O = isL ? xl_bf : xr_bf;
  int cb = isL ? col0 : (col0 - 1024);
  float bias4[4];
  #pragma unroll
  for (int ni=0;ni<4;ni++) bias4[ni] = bias[cb + wn*64 + ni*16 + l16];
  #pragma unroll
  for (int mi=0;mi<4;mi++)
    #pragma unroll
    for (int ni=0;ni<4;ni++) {
      int col = cb + wn*64 + ni*16 + l16;
      #pragma unroll
      for (int r=0;r<4;r++) {
        int row = row0 + wm*64 + mi*16 + quad*4 + r;
        O[(size_t)row*1024 + col] = f2bf(acc[mi][ni][r] + bias4[ni]);
      }
    }
}

// ---------------- we-GEMM + fused attention logits (exact R7 form) ----------------
__global__ __launch_bounds__(256) void k_mfma_we(
    const unsigned short* __restrict__ E_bf, const unsigned short* __restrict__ Wge_bf,
    const int* __restrict__ ei,
    const unsigned short* __restrict__ xl_bf, const unsigned short* __restrict__ xr_bf,
    const float* __restrict__ att, float* __restrict__ logit_part) {
  __shared__ unsigned short As[2][4096];
  __shared__ unsigned short Bs[2][4096];
  __shared__ float tmp[128];
  int blk = blockIdx.x;
  int xcd = blk & 7, slot = blk >> 3;
  int bx = xcd*64 + (slot >> 3), by = slot & 7;
  int row0 = bx*128, col0 = by*128;
  int tid = threadIdx.x;
  int w = tid >> 6, lane = tid & 63;
  int wm = w >> 1, wn = w & 1;
  int quad = lane >> 4, l16 = lane & 15;
  int ldoff = w*512 + lane*8;
  const unsigned short* gA = E_bf  + (size_t)(row0 + w*16 + l16)*512 + quad*8;
  const unsigned short* gB = Wge_bf + (size_t)(col0 + w*16 + l16)*512 + quad*8;
  f32x4 acc[4][4];
  #pragma unroll
  for (int i=0;i<4;i++)
    #pragma unroll
    for (int j=0;j<4;j++) acc[i][j] = (f32x4){0.f,0.f,0.f,0.f};

  {
    uint4 a0 = *(const uint4*)(gA);
    uint4 a1 = *(const uint4*)(gA + 32768);
    uint4 b0 = *(const uint4*)(gB);
    uint4 b1 = *(const uint4*)(gB + 32768);
    *(uint4*)&As[0][ldoff] = a0; *(uint4*)&As[0][2048+ldoff] = a1;
    *(uint4*)&Bs[0][ldoff] = b0; *(uint4*)&Bs[0][2048+ldoff] = b1;
  }
  __syncthreads();
  int cur = 0;
  #pragma unroll 2
  for (int k0 = 32; k0 <= 512; k0 += 32) {
    uint4 na0, na1, nb0, nb1;
    bool more = (k0 < 512);
    if (more) {
      na0 = *(const uint4*)(gA + k0);
      na1 = *(const uint4*)(gA + 32768 + k0);
      nb0 = *(const uint4*)(gB + k0);
      nb1 = *(const uint4*)(gB + 32768 + k0);
    }
    bf16x8 af[4], bfr[4];
    #pragma unroll
    for (int mi=0;mi<4;mi++)
      af[mi] = *(const bf16x8*)&As[cur][(wm*4+mi)*512 + quad*128 + l16*8];
    #pragma unroll
    for (int ni=0;ni<4;ni++)
      bfr[ni] = *(const bf16x8*)&Bs[cur][(wn*4+ni)*512 + quad*128 + l16*8];
    #pragma unroll
    for (int mi=0;mi<4;mi++)
      #pragma unroll
      for (int ni=0;ni<4;ni++)
        acc[mi][ni] = __builtin_amdgcn_mfma_f32_16x16x32_bf16(af[mi], bfr[ni], acc[mi][ni], 0, 0, 0);
    if (more) {
      *(uint4*)&As[cur^1][ldoff] = na0; *(uint4*)&As[cur^1][2048+ldoff] = na1;
      *(uint4*)&Bs[cur^1][ldoff] = nb0; *(uint4*)&Bs[cur^1][2048+ldoff] = nb1;
    }
    __syncthreads();
    cur ^= 1;
  }
  float att4[4];
  #pragma unroll
  for (int ni=0;ni<4;ni++) att4[ni] = att[col0 + wn*64 + ni*16 + l16];
  float pv[4][4];
  #pragma unroll
  for (int mi=0;mi<4;mi++) {
    #pragma unroll
    for (int r=0;r<4;r++) {
      int e = row0 + wm*64 + mi*16 + quad*4 + r;
      int s = ei[e], d = ei[N_EDGES + e];
      const unsigned short* xlr = xl_bf + (size_t)s*1024;
      const unsigned short* xrr = xr_bf + (size_t)d*1024;
      float p = 0.f;
      #pragma unroll
      for (int ni=0;ni<4;ni++) {
        int col = col0 + wn*64 + ni*16 + l16;
        float z = acc[mi][ni][r] + bf2f(xlr[col]) + bf2f(xrr[col]);
        z = leaky02(z);
        p += z*att4[ni];
      }
      p += __shfl_down(p, 8, 16);
      p += __shfl_down(p, 4, 16);
      p += __shfl_down(p, 2, 16);
      p += __shfl_down(p, 1, 16);
      pv[mi][r] = p;
    }
  }
  if (wn == 1 && l16 == 0) {
    #pragma unroll
    for (int mi=0;mi<4;mi++)
      #pragma unroll
      for (int r=0;r<4;r++)
        tmp[wm*64 + mi*16 + quad*4 + r] = pv[mi][r];
  }
  __syncthreads();
  if (wn == 0 && l16 == 0) {
    #pragma unroll
    for (int mi=0;mi<4;mi++)
      #pragma unroll
      for (int r=0;r<4;r++) {
        int le = wm*64 + mi*16 + quad*4 + r;
        logit_part[(size_t)(row0 + le)*8 + by] = pv[mi][r] + tmp[le];
      }
  }
}

// ---------------- fused: self-loop logit + softmax + GAT aggregation ----------------
__global__ __launch_bounds__(256) void k_softmax_gat(
    const int* __restrict__ ei, const int* __restrict__ rowptr, const int* __restrict__ csr,
    const float* __restrict__ logit_part,
    const unsigned short* __restrict__ xl_bf, const unsigned short* __restrict__ xr_bf,
    const float* __restrict__ we_loop, const float* __restrict__ att,
    const float* __restrict__ bgat,
    float* __restrict__ alpha, unsigned short* __restrict__ gat_bf) {
  __shared__ float sl[256];
  __shared__ int   se[256];
  __shared__ float red[256];
  int blk = blockIdx.x;
  int n = ((blk & 7) << 11) + (blk >> 3);
  int tid = threadIdx.x;
  {
    ushort4 a = ((const ushort4*)(xl_bf + (size_t)n*1024))[tid];
    ushort4 b = ((const ushort4*)(xr_bf + (size_t)n*1024))[tid];
    float4 c = ((const float4*)we_loop)[tid];
    float4 t = ((const float4*)att)[tid];
    float s = 0.f;
    s += leaky02(bf2f(a.x)+bf2f(b.x)+c.x)*t.x;
    s += leaky02(bf2f(a.y)+bf2f(b.y)+c.y)*t.y;
    s += leaky02(bf2f(a.z)+bf2f(b.z)+c.z)*t.z;
    s += leaky02(bf2f(a.w)+bf2f(b.w)+c.w)*t.w;
    red[tid] = s;
  }
  __syncthreads();
  #pragma unroll
  for (int off=128; off; off>>=1){ if (tid<off) red[tid] += red[tid+off]; __syncthreads(); }
  float sll = red[0];
  __syncthreads();

  int beg = rowptr[n], end = rowptr[n+1], cnt = end - beg;
  float m = -1e30f;
  for (int p = beg+tid; p < end; p += 256) {
    int e = csr[p];
    float lg;
    if (e < N_EDGES) {
      const float4* lp = (const float4*)(logit_part + (size_t)e*8);
      float4 q0 = lp[0], q1 = lp[1];
      lg = q0.x+q0.y+q0.z+q0.w+q1.x+q1.y+q1.z+q1.w;
    } else lg = sll;
    int idx = p - beg;
    if (idx < 256) { se[idx] = e; sl[idx] = lg; }
    m = fmaxf(m, lg);
  }
  red[tid] = m; __syncthreads();
  #pragma unroll
  for (int off=128; off; off>>=1){ if (tid<off) red[tid] = fmaxf(red[tid], red[tid+off]); __syncthreads(); }
  m = red[0];
  __syncthreads();
  float ss = 0.f;
  for (int p = beg+tid; p < end; p += 256) {
    int idx = p - beg;
    ss += expf(sl[idx] - m);
  }
  red[tid] = ss; __syncthreads();
  #pragma unroll
  for (int off=128; off; off>>=1){ if (tid<off) red[tid] += red[tid+off]; __syncthreads(); }
  float inv = 1.f/(red[0] + 1e-16f);
  __syncthreads();
  for (int p = beg+tid; p < end; p += 256) {
    int idx = p - beg;
    float a = expf(sl[idx] - m)*inv;
    alpha[se[idx]] = a;
    sl[idx] = a;
  }
  __syncthreads();
  float4 acc = ((const float4*)bgat)[tid];
  for (int p = 0; p < cnt; p++) {
    float a = sl[p]; int e = se[p];
    int s = (e < N_EDGES) ? ei[e] : (e - N_EDGES);
    ushort4 v = ((const ushort4*)(xl_bf + (size_t)s*1024))[tid];
    acc.x += a*bf2f(v.x); acc.y += a*bf2f(v.y); acc.z += a*bf2f(v.z); acc.w += a*bf2f(v.w);
  }
  ushort4 o; o.x=f2bf(acc.x); o.y=f2bf(acc.y); o.z=f2bf(acc.z); o.w=f2bf(acc.w);
  ((ushort4*)(gat_bf + (size_t)n*1024))[tid] = o;
}

// ---------------- per-graph weighted sums of gat (ushort4 vectorized) ----------------
// grid (32, 4): y = node chunk of 128; thread handles 4 consecutive cols
__global__ __launch_bounds__(256) void k_nodepool(
    const unsigned short* __restrict__ gat_bf, const int* __restrict__ odeg,
    const int* __restrict__ rowptr,
    float* __restrict__ P_G, float* __restrict__ P_DG, float* __restrict__ P_gat) {
  int b = blockIdx.x, nc = blockIdx.y;
  int c4 = threadIdx.x;                 // cols c4*4 .. c4*4+3
  float a1[4]={0,0,0,0}, a2[4]={0,0,0,0}, a3[4]={0,0,0,0};
  int n0 = b*512 + nc*128;
  for (int i=0;i<128;i++){
    int n = n0 + i;
    ushort4 g4 = ((const ushort4*)(gat_bf + (size_t)n*1024))[c4];
    float od = (float)odeg[n];
    float dg = (float)(rowptr[n+1]-rowptr[n]);
    float g0 = bf2f(g4.x), g1 = bf2f(g4.y), g2 = bf2f(g4.z), g3 = bf2f(g4.w);
    a1[0]+=od*g0; a1[1]+=od*g1; a1[2]+=od*g2; a1[3]+=od*g3;
    a2[0]+=dg*g0; a2[1]+=dg*g1; a2[2]+=dg*g2; a2[3]+=dg*g3;
    a3[0]+=g0; a3[1]+=g1; a3[2]+=g2; a3[3]+=g3;
  }
  #pragma unroll
  for (int j=0;j<4;j++){
    atomicAdd(&P_G [b*1024 + c4*4+j], a1[j]);
    atomicAdd(&P_DG[b*1024 + c4*4+j], a2[j]);
    atomicAdd(&P_gat[b*1024 + c4*4+j], a3[j]);
  }
}

// ---------------- edge pooling ----------------
__global__ __launch_bounds__(256) void k_edgepool(
    const float* __restrict__ ea, const float* __restrict__ We, const float* __restrict__ be,
    const float* __restrict__ alpha, float* __restrict__ P_S, float* __restrict__ pe) {
  __shared__ float sea[640];
  __shared__ float sal[128];
  int b = blockIdx.x, chy = blockIdx.y, tid = threadIdx.x;
  int mode = (chy < 20) ? 0 : 1;
  int ch = (chy < 20) ? chy : (chy - 20);
  int c1 = tid, c2 = tid + 256;
  bool v2 = (c2 < 511);
  float w1[5], w2[5]={0,0,0,0,0}, b1v, b2v=0.f;
  #pragma unroll
  for (int q=0;q<5;q++) w1[q] = We[c1*5+q];
  b1v = be[c1];
  if (v2) {
    #pragma unroll
    for (int q=0;q<5;q++) w2[q] = We[c2*5+q];
    b2v = be[c2];
  }
  int base = (mode == 0)
    ? ((ch < 16) ? (b*2048 + ch*128) : (N_EDGES + b*512 + (ch-16)*128))
    : (b*2560 + ch*128);
  for (int i=tid;i<640;i+=256){
    int r = base + i/5;
    sea[i] = (r < N_EDGES) ? ea[(size_t)r*5 + (i%5)] : 1.0f;
  }
  for (int i=tid;i<128;i+=256) sal[i] = alpha[base + i];
  __syncthreads();
  float acc1 = 0.f, acc2 = 0.f;
  for (int rr=0; rr<128; rr++) {
    const float* er = &sea[rr*5];
    acc1 += leaky01(b1v + er[0]*w1[0]+er[1]*w1[1]+er[2]*w1[2]+er[3]*w1[3]+er[4]*w1[4]);
    if (v2) acc2 += leaky01(b2v + er[0]*w2[0]+er[1]*w2[1]+er[2]*w2[2]+er[3]*w2[3]+er[4]*w2[4]);
    else    acc2 += sal[rr];
  }
  if (mode == 0) {
    atomicAdd(&P_S[b*512+c1], acc1);
    atomicAdd(&P_S[b*512+c2], acc2);
  } else {
    const float sc = 1.f/2560.f;
    atomicAdd(&pe[b*512+c1], acc1*sc);
    atomicAdd(&pe[b*512+c2], acc2*sc);
  }
}

// ---------------- pn via tiny fused GEMMs (XCD-swizzled) ----------------
// grid 512 flat: xcd=blk&7, slot=blk>>3; colgrp = xcd*2+(slot&1); b = slot>>1
// -> all 32 b-blocks of one col-group on one XCD: weights L2-resident.
__global__ __launch_bounds__(256) void k_pn(
    const float* __restrict__ P_G, const float* __restrict__ P_DG,
    const float* __restrict__ P_S, const float* __restrict__ P_gat,
    const float* __restrict__ Wm, const float* __restrict__ bm,
    const float* __restrict__ Wmi, const float* __restrict__ bmi,
    const float* __restrict__ Wce, const float* __restrict__ bce,
    float* __restrict__ pn) {
  __shared__ float sPg[1024], sPdg[1024], sPs[512];
  int blk = blockIdx.x;
  int xcd = blk & 7, slot = blk >> 3;
  int colgrp = xcd*2 + (slot & 1);
  int b = slot >> 1;
  int col0 = colgrp*64;
  int tid = threadIdx.x, w = tid >> 6, lane = tid & 63;
  for (int i=tid;i<1024;i+=256){ sPg[i]=P_G[b*1024+i]; sPdg[i]=P_DG[b*1024+i]; }
  for (int i=tid;i<512;i+=256) sPs[i]=P_S[b*512+i];
  __syncthreads();
  for (int c=0;c<16;c++){
    int j = col0 + w*16 + c;
    const float* wm  = Wm  + (size_t)j*1024;
    const float* wmi = Wmi + (size_t)j*1024;
    const float* wce = Wce + (size_t)j*512;
    float s = 0.f;
    #pragma unroll 4
    for (int i=0;i<16;i++){ int k = lane + i*64; s += sPg[k]*wm[k] + sPdg[k]*wmi[k]; }
    #pragma unroll 4
    for (int i=0;i<8;i++){ int k = lane + i*64; s += sPs[k]*wce[k]; }
    #pragma unroll
    for (int off=32; off; off>>=1) s += __shfl_down(s, off);
    if (lane == 0) {
      pn[b*1024+j] = (s + P_gat[b*1024+j] + 2560.f*(bm[j]+bmi[j]+bce[j])) * (1.f/512.f);
    }
  }
}

// ---------------- final head ----------------
__global__ __launch_bounds__(256) void k_final(
    const float* __restrict__ pn, const float* __restrict__ pe, const float* __restrict__ yg,
    const float* __restrict__ W1, const float* __restrict__ b1,
    const float* __restrict__ W2, const float* __restrict__ b2,
    float* __restrict__ out) {
  __shared__ float pooled[2048];
  __shared__ float red[256];
  int b = blockIdx.x, tid = threadIdx.x;
  for (int i=tid;i<1024;i+=256) pooled[i]      = pn[b*1024+i];
  for (int i=tid;i<512;i+=256)  pooled[1024+i] = pe[b*512+i];
  for (int i=tid;i<512;i+=256)  pooled[1536+i] = yg[b*512+i];
  __syncthreads();
  const float4* w4 = (const float4*)(W1 + (size_t)tid*2048);
  const float4* p4 = (const float4*)pooled;
  float s = b1[tid];
  for (int k=0;k<512;k++){
    float4 w = w4[k]; float4 p = p4[k];
    s += w.x*p.x + w.y*p.y + w.z*p.z + w.w*p.w;
  }
  s = leaky01(s);
  red[tid] = s * W2[tid];
  __syncthreads();
  for (int off=128; off; off>>=1){
    if (tid < off) red[tid] += red[tid+off];
    __syncthreads();
  }
  if (tid == 0){
    float o = red[0] + b2[0];
    out[b] = 1.f/(1.f+expf(-o));
  }
}

// ---------------- launcher ----------------
extern "C" void kernel_launch(void* const* d_in, const int* in_sizes, int n_in,
                              void* d_out, int out_size, void* d_ws, size_t ws_size,
                              hipStream_t stream) {
  const float* x   = (const float*)d_in[0];
  const int*   ei  = (const int*)  d_in[1];
  const float* ea  = (const float*)d_in[2];
  const float* y   = (const float*)d_in[3];
  const float* Wn  = (const float*)d_in[5];
  const float* bn  = (const float*)d_in[6];
  const float* We  = (const float*)d_in[7];
  const float* be  = (const float*)d_in[8];
  const float* Wg  = (const float*)d_in[9];
  const float* bg  = (const float*)d_in[10];
  const float* Wl  = (const float*)d_in[11];
  const float* bl  = (const float*)d_in[12];
  const float* Wr  = (const float*)d_in[13];
  const float* br  = (const float*)d_in[14];
  const float* Wge = (const float*)d_in[15];
  const float* att = (const float*)d_in[16];
  const float* bgat= (const float*)d_in[17];
  const float* Wm  = (const float*)d_in[18];
  const float* bm  = (const float*)d_in[19];
  const float* Wmi = (const float*)d_in[20];
  const float* bmi = (const float*)d_in[21];
  const float* Wce = (const float*)d_in[22];
  const float* bce = (const float*)d_in[23];
  const float* W1  = (const float*)d_in[24];
  const float* b1  = (const float*)d_in[25];
  const float* W2  = (const float*)d_in[26];
  const float* b2  = (const float*)d_in[27];
  float* out = (float*)d_out;

  char* ws = (char*)d_ws;
  unsigned short* xl_bf  = (unsigned short*)(ws + OFF_XL);
  unsigned short* xr_bf  = (unsigned short*)(ws + OFF_XR);
  unsigned short* gat_bf = (unsigned short*)(ws + OFF_XR);   // alias
  unsigned short* E_bf   = (unsigned short*)(ws + OFF_EBF);
  unsigned short* h_bf   = (unsigned short*)(ws + OFF_HBF);
  unsigned short* Wcat   = (unsigned short*)(ws + OFF_WCAT);
  unsigned short* Wge_p  = (unsigned short*)(ws + OFF_WGEP);
  float* lpart  = (float*)(ws + OFF_LPART);
  float* zone   = (float*)(ws + OFF_DEG);
  int*   deg    = (int*)  (ws + OFF_DEG);
  int*   odeg   = (int*)  (ws + OFF_ODEG);
  int*   cursor = (int*)  (ws + OFF_CURS);
  float* P_G    = (float*)(ws + OFF_PG);
  float* P_DG   = (float*)(ws + OFF_PDG);
  float* P_gat  = (float*)(ws + OFF_PGAT);
  float* P_S    = (float*)(ws + OFF_PS);
  float* pe     = (float*)(ws + OFF_PE);
  int*   rowptr = (int*)  (ws + OFF_ROWP);
  int*   csr    = (int*)  (ws + OFF_CSR);
  float* alpha  = (float*)(ws + OFF_ALPHA);
  float* we_loop= (float*)(ws + OFF_WLOOP);
  float* yg     = (float*)(ws + OFF_YG);
  float* pn     = (float*)(ws + OFF_PN);

  k_prep0<<<dim3(4340), dim3(256), 0, stream>>>(x, Wn, bn, Wl, Wr, Wge, y, Wg, bg, We, be,
                                                zone, h_bf, Wcat, Wge_p, yg, we_loop);
  k_gemm_xlxr<<<dim3(2048), dim3(256), 0, stream>>>(h_bf, Wcat, bl, br, xl_bf, xr_bf);
  k_prep_e<<<dim3(16704), dim3(256), 0, stream>>>(ea, We, be, E_bf, ei, deg, odeg);
  k_mfma_we<<<dim3(4096), dim3(256), 0, stream>>>(E_bf, Wge_p, ei, xl_bf, xr_bf, att, lpart);
  k_scan<<<dim3(1), dim3(1024), 0, stream>>>(deg, rowptr);
  k_fill_csr<<<dim3(320), dim3(256), 0, stream>>>(ei, rowptr, cursor, csr);
  k_softmax_gat<<<dim3(16384), dim3(256), 0, stream>>>(ei, rowptr, csr, lpart, xl_bf, xr_bf,
                                                       we_loop, att, bgat, alpha, gat_bf);
  k_nodepool<<<dim3(32,4), dim3(256), 0, stream>>>(gat_bf, odeg, rowptr, P_G, P_DG, P_gat);
  k_edgepool<<<dim3(32,40), dim3(256), 0, stream>>>(ea, We, be, alpha, P_S, pe);
  k_pn<<<dim3(512), dim3(256), 0, stream>>>(P_G, P_DG, P_S, P_gat, Wm, bm, Wmi, bmi, Wce, bce, pn);
  k_final<<<dim3(32), dim3(256), 0, stream>>>(pn, pe, yg, W1, b1, W2, b2, out);
}

// Round 11
// 626.091 us; speedup vs baseline: 1.1721x; 1.0085x over previous
//
#include <hip/hip_runtime.h>
#include <cstdint>
#include <cstddef>

#define N_NODES 16384
#define N_EDGES 65536
#define ETOT    81920
#define B_GR    32

typedef __attribute__((ext_vector_type(8))) short bf16x8;
typedef __attribute__((ext_vector_type(4))) float f32x4;

// ---------------- workspace layout (bytes), peak 138,285,056 ----------------
static constexpr size_t OFF_XL    = 0;              // 33,554,432
static constexpr size_t OFF_XR    = 33554432ULL;    // 33,554,432 (gat_bf aliases)
static constexpr size_t OFF_EBF   = 67108864ULL;    // 67,108,864  E_bf
static constexpr size_t OFF_HBF   = 67108864ULL;    //   alias: h_bf (dead after xlxr GEMM)
static constexpr size_t OFF_WCAT  = 83886080ULL;    //   alias: Wcat (dead after xlxr GEMM)
static constexpr size_t OFF_ROWP  = 67108864ULL;    //   alias: rowptr (after k_mfma_we)
static constexpr size_t OFF_CSR   = 67174656ULL;    //   alias
static constexpr size_t OFF_ALPHA = 67502336ULL;    //   alias
static constexpr size_t OFF_WGEP  = 134217728ULL;   // 1,048,576
static constexpr size_t OFF_LPART = 135266304ULL;   // 2,097,152  logit_part [65536x8 f32]
// ---- zero zone (720,896 B) ----
static constexpr size_t OFF_DEG   = 137363456ULL;
static constexpr size_t OFF_ODEG  = 137428992ULL;
static constexpr size_t OFF_CURS  = 137494528ULL;
static constexpr size_t OFF_PG    = 137560064ULL;
static constexpr size_t OFF_PDG   = 137691136ULL;
static constexpr size_t OFF_PGAT  = 137822208ULL;
static constexpr size_t OFF_PS    = 137953280ULL;
static constexpr size_t OFF_PE    = 138018816ULL;
// ---- end zero zone ----
static constexpr size_t OFF_WLOOP = 138084352ULL;
static constexpr size_t OFF_YG    = 138088448ULL;
static constexpr size_t OFF_PN    = 138153984ULL;
// end = 138,285,056

__device__ __forceinline__ float leaky01(float v){ return v >= 0.f ? v : 0.01f*v; }
__device__ __forceinline__ float leaky02(float v){ return v >= 0.f ? v : 0.2f*v; }
__device__ __forceinline__ unsigned short f2bf(float f){
  union { float f; unsigned u; } v; v.f = f;
  unsigned r = v.u + 0x7FFFu + ((v.u >> 16) & 1u);
  return (unsigned short)(r >> 16);
}
__device__ __forceinline__ float bf2f(unsigned short h){
  union { unsigned u; float f; } v; v.u = ((unsigned)h) << 16;
  return v.f;
}

// ---------------- merged prep ----------------
__global__ __launch_bounds__(256) void k_prep0(
    const float* __restrict__ x, const float* __restrict__ Wn, const float* __restrict__ bn,
    const float* __restrict__ Wl, const float* __restrict__ Wr,
    const float* __restrict__ Wge, const float* __restrict__ y,
    const float* __restrict__ Wg, const float* __restrict__ bg,
    const float* __restrict__ We, const float* __restrict__ be,
    float* __restrict__ zone, unsigned short* __restrict__ h_bf,
    unsigned short* __restrict__ Wcat, unsigned short* __restrict__ Wge_p,
    float* __restrict__ yg, float* __restrict__ we_loop) {
  __shared__ float e_lds[512];
  int bx = blockIdx.x, tid = threadIdx.x;
  if (bx < 176) {
    ((float4*)zone)[bx*256 + tid] = (float4){0.f,0.f,0.f,0.f};
  } else if (bx < 1200) {               // h_bf
    int gid = (bx-176)*256 + tid;
    int base = gid*8;
    int n = base >> 9, j = base & 511;
    float xv = x[n];
    float4 w0 = *(const float4*)(Wn + j);
    float4 w1 = *(const float4*)(Wn + j + 4);
    float4 b0 = *(const float4*)(bn + j);
    float4 b1 = *(const float4*)(bn + j + 4);
    unsigned short o[8];
    o[0]=f2bf(leaky01(xv*w0.x+b0.x)); o[1]=f2bf(leaky01(xv*w0.y+b0.y));
    o[2]=f2bf(leaky01(xv*w0.z+b0.z)); o[3]=f2bf(leaky01(xv*w0.w+b0.w));
    o[4]=f2bf(leaky01(xv*w1.x+b1.x)); o[5]=f2bf(leaky01(xv*w1.y+b1.y));
    o[6]=f2bf(leaky01(xv*w1.z+b1.z)); o[7]=f2bf(leaky01(xv*w1.w+b1.w));
    ((uint4*)h_bf)[gid] = *(const uint4*)o;
  } else if (bx < 2224) {               // Wcat
    int i = (bx-1200)*256 + tid;
    int base = i*4;
    const float* src = (base < 524288) ? (Wl + base) : (Wr + base - 524288);
    float4 v = *(const float4*)src;
    ushort4 o; o.x=f2bf(v.x); o.y=f2bf(v.y); o.z=f2bf(v.z); o.w=f2bf(v.w);
    ((ushort4*)Wcat)[i] = o;
  } else if (bx < 4272) {               // Wge_p
    int gid = (bx-2224)*256 + tid;
    int j = gid >> 9, k = gid & 511;
    Wge_p[gid] = (k < 511) ? f2bf(Wge[(size_t)j*511 + k]) : (unsigned short)0;
  } else if (bx < 4336) {               // yg
    int gid = (bx-4272)*256 + tid;
    int b = gid >> 9, j = gid & 511;
    float s = bg[j];
    #pragma unroll
    for (int k=0;k<5;k++) s += y[b*5+k]*Wg[j*5+k];
    yg[gid] = leaky01(s);
  } else {                              // we_loop
    for (int c = tid; c < 512; c += 256) {
      float v = 0.f;
      if (c < 511) {
        float s = be[c];
        #pragma unroll
        for (int q=0;q<5;q++) s += We[c*5+q];
        v = leaky01(s);
      }
      e_lds[c] = v;
    }
    __syncthreads();
    int j = (bx-4336)*256 + tid;
    float s = 0.f;
    for (int k=0;k<511;k++) s += e_lds[k]*Wge[(size_t)j*511+k];
    we_loop[j] = s;
  }
}

// ---------------- E_bf prep + degree counts (merged) ----------------
__global__ __launch_bounds__(256) void k_prep_e(
    const float* __restrict__ ea, const float* __restrict__ We, const float* __restrict__ be,
    unsigned short* __restrict__ E_bf,
    const int* __restrict__ ei, int* __restrict__ deg, int* __restrict__ odeg) {
  int blk = blockIdx.x;
  if (blk < 16384) {
    int gid = blk*256 + threadIdx.x;
    int e = gid >> 6, cg = gid & 63;
    int c0 = cg*8;
    const float* e5 = ea + (size_t)e*5;
    float a0=e5[0], a1=e5[1], a2=e5[2], a3=e5[3], a4=e5[4];
    unsigned short o[8];
    #pragma unroll
    for (int j=0;j<8;j++) {
      int c = c0 + j;
      float v = 0.f;
      if (c < 511) {
        const float* w = We + c*5;
        float s = be[c] + a0*w[0] + a1*w[1] + a2*w[2] + a3*w[3] + a4*w[4];
        v = leaky01(s);
      }
      o[j] = f2bf(v);
    }
    ((uint4*)E_bf)[gid] = *(const uint4*)o;
  } else {
    int i = (blk-16384)*256 + threadIdx.x;
    int s, d;
    if (i < N_EDGES) { s = ei[i]; d = ei[N_EDGES + i]; }
    else { s = i - N_EDGES; d = s; }
    atomicAdd(&deg[d], 1);
    atomicAdd(&odeg[s], 1);
  }
}

// ---------------- CSR build ----------------
__global__ __launch_bounds__(1024) void k_scan(const int* __restrict__ deg, int* __restrict__ rowptr) {
  __shared__ int sums[1024];
  int t = threadIdx.x;
  int local[16]; int s = 0;
  #pragma unroll
  for (int i=0;i<16;i++){ local[i] = deg[t*16+i]; s += local[i]; }
  sums[t] = s; __syncthreads();
  for (int off=1; off<1024; off<<=1) {
    int v = (t >= off) ? sums[t-off] : 0;
    __syncthreads();
    sums[t] += v;
    __syncthreads();
  }
  int run = (t==0) ? 0 : sums[t-1];
  if (t==0) rowptr[0] = 0;
  #pragma unroll
  for (int i=0;i<16;i++){ run += local[i]; rowptr[t*16+i+1] = run; }
}

__global__ void k_fill_csr(const int* __restrict__ ei, const int* __restrict__ rowptr,
                           int* __restrict__ cursor, int* __restrict__ csr) {
  int i = blockIdx.x*blockDim.x + threadIdx.x;
  int d = (i < N_EDGES) ? ei[N_EDGES + i] : (i - N_EDGES);
  int pos = rowptr[d] + atomicAdd(&cursor[d], 1);
  csr[pos] = i;
}

// ================= double-buffered MFMA GEMM core (R7, proven) =================

// ---------------- combined xl/xr MFMA GEMM ----------------
__global__ __launch_bounds__(256) void k_gemm_xlxr(
    const unsigned short* __restrict__ h_bf, const unsigned short* __restrict__ Wcat,
    const float* __restrict__ bl, const float* __restrict__ br,
    unsigned short* __restrict__ xl_bf, unsigned short* __restrict__ xr_bf) {
  __shared__ unsigned short As[2][4096];
  __shared__ unsigned short Bs[2][4096];
  int blk = blockIdx.x;
  int xcd = blk & 7, slot = blk >> 3;
  int bx = xcd*16 + (slot >> 4), by = slot & 15;
  int row0 = bx*128, col0 = by*128;
  int tid = threadIdx.x;
  int w = tid >> 6, lane = tid & 63;
  int wm = w >> 1, wn = w & 1;
  int quad = lane >> 4, l16 = lane & 15;
  int ldoff = w*512 + lane*8;
  const unsigned short* gA = h_bf + (size_t)(row0 + w*16 + l16)*512 + quad*8;
  const unsigned short* gB = Wcat + (size_t)(col0 + w*16 + l16)*512 + quad*8;
  f32x4 acc[4][4];
  #pragma unroll
  for (int i=0;i<4;i++)
    #pragma unroll
    for (int j=0;j<4;j++) acc[i][j] = (f32x4){0.f,0.f,0.f,0.f};

  {
    uint4 a0 = *(const uint4*)(gA);
    uint4 a1 = *(const uint4*)(gA + 32768);
    uint4 b0 = *(const uint4*)(gB);
    uint4 b1 = *(const uint4*)(gB + 32768);
    *(uint4*)&As[0][ldoff] = a0; *(uint4*)&As[0][2048+ldoff] = a1;
    *(uint4*)&Bs[0][ldoff] = b0; *(uint4*)&Bs[0][2048+ldoff] = b1;
  }
  __syncthreads();
  int cur = 0;
  #pragma unroll 2
  for (int k0 = 32; k0 <= 512; k0 += 32) {
    uint4 na0, na1, nb0, nb1;
    bool more = (k0 < 512);
    if (more) {
      na0 = *(const uint4*)(gA + k0);
      na1 = *(const uint4*)(gA + 32768 + k0);
      nb0 = *(const uint4*)(gB + k0);
      nb1 = *(const uint4*)(gB + 32768 + k0);
    }
    bf16x8 af[4], bfr[4];
    #pragma unroll
    for (int mi=0;mi<4;mi++)
      af[mi] = *(const bf16x8*)&As[cur][(wm*4+mi)*512 + quad*128 + l16*8];
    #pragma unroll
    for (int ni=0;ni<4;ni++)
      bfr[ni] = *(const bf16x8*)&Bs[cur][(wn*4+ni)*512 + quad*128 + l16*8];
    #pragma unroll
    for (int mi=0;mi<4;mi++)
      #pragma unroll
      for (int ni=0;ni<4;ni++)
        acc[mi][ni] = __builtin_amdgcn_mfma_f32_16x16x32_bf16(af[mi], bfr[ni], acc[mi][ni], 0, 0, 0);
    if (more) {
      *(uint4*)&As[cur^1][ldoff] = na0; *(uint4*)&As[cur^1][2048+ldoff] = na1;
      *(uint4*)&Bs[cur^1][ldoff] = nb0; *(uint4*)&Bs[cur^1][2048+ldoff] = nb1;
    }
    __syncthreads();
    cur ^= 1;
  }
  bool isL = (by < 8);
  const float* bias = isL ? bl : br;
  unsigned short* O = isL ? xl_bf : xr_bf;
  int cb = isL ? col0 : (col0 - 1024);
  float bias4[4];
  #pragma unroll
  for (int ni=0;ni<4;ni++) bias4[ni] = bias[cb + wn*64 + ni*16 + l16];
  #pragma unroll
  for (int mi=0;mi<4;mi++)
    #pragma unroll
    for (int ni=0;ni<4;ni++) {
      int col = cb + wn*64 + ni*16 + l16;
      #pragma unroll
      for (int r=0;r<4;r++) {
        int row = row0 + wm*64 + mi*16 + quad*4 + r;
        O[(size_t)row*1024 + col] = f2bf(acc[mi][ni][r] + bias4[ni]);
      }
    }
}

// ---------------- we-GEMM + fused attention logits (exact R7 form) ----------------
__global__ __launch_bounds__(256) void k_mfma_we(
    const unsigned short* __restrict__ E_bf, const unsigned short* __restrict__ Wge_bf,
    const int* __restrict__ ei,
    const unsigned short* __restrict__ xl_bf, const unsigned short* __restrict__ xr_bf,
    const float* __restrict__ att, float* __restrict__ logit_part) {
  __shared__ unsigned short As[2][4096];
  __shared__ unsigned short Bs[2][4096];
  __shared__ float tmp[128];
  int blk = blockIdx.x;
  int xcd = blk & 7, slot = blk >> 3;
  int bx = xcd*64 + (slot >> 3), by = slot & 7;
  int row0 = bx*128, col0 = by*128;
  int tid = threadIdx.x;
  int w = tid >> 6, lane = tid & 63;
  int wm = w >> 1, wn = w & 1;
  int quad = lane >> 4, l16 = lane & 15;
  int ldoff = w*512 + lane*8;
  const unsigned short* gA = E_bf  + (size_t)(row0 + w*16 + l16)*512 + quad*8;
  const unsigned short* gB = Wge_bf + (size_t)(col0 + w*16 + l16)*512 + quad*8;
  f32x4 acc[4][4];
  #pragma unroll
  for (int i=0;i<4;i++)
    #pragma unroll
    for (int j=0;j<4;j++) acc[i][j] = (f32x4){0.f,0.f,0.f,0.f};

  {
    uint4 a0 = *(const uint4*)(gA);
    uint4 a1 = *(const uint4*)(gA + 32768);
    uint4 b0 = *(const uint4*)(gB);
    uint4 b1 = *(const uint4*)(gB + 32768);
    *(uint4*)&As[0][ldoff] = a0; *(uint4*)&As[0][2048+ldoff] = a1;
    *(uint4*)&Bs[0][ldoff] = b0; *(uint4*)&Bs[0][2048+ldoff] = b1;
  }
  __syncthreads();
  int cur = 0;
  #pragma unroll 2
  for (int k0 = 32; k0 <= 512; k0 += 32) {
    uint4 na0, na1, nb0, nb1;
    bool more = (k0 < 512);
    if (more) {
      na0 = *(const uint4*)(gA + k0);
      na1 = *(const uint4*)(gA + 32768 + k0);
      nb0 = *(const uint4*)(gB + k0);
      nb1 = *(const uint4*)(gB + 32768 + k0);
    }
    bf16x8 af[4], bfr[4];
    #pragma unroll
    for (int mi=0;mi<4;mi++)
      af[mi] = *(const bf16x8*)&As[cur][(wm*4+mi)*512 + quad*128 + l16*8];
    #pragma unroll
    for (int ni=0;ni<4;ni++)
      bfr[ni] = *(const bf16x8*)&Bs[cur][(wn*4+ni)*512 + quad*128 + l16*8];
    #pragma unroll
    for (int mi=0;mi<4;mi++)
      #pragma unroll
      for (int ni=0;ni<4;ni++)
        acc[mi][ni] = __builtin_amdgcn_mfma_f32_16x16x32_bf16(af[mi], bfr[ni], acc[mi][ni], 0, 0, 0);
    if (more) {
      *(uint4*)&As[cur^1][ldoff] = na0; *(uint4*)&As[cur^1][2048+ldoff] = na1;
      *(uint4*)&Bs[cur^1][ldoff] = nb0; *(uint4*)&Bs[cur^1][2048+ldoff] = nb1;
    }
    __syncthreads();
    cur ^= 1;
  }
  float att4[4];
  #pragma unroll
  for (int ni=0;ni<4;ni++) att4[ni] = att[col0 + wn*64 + ni*16 + l16];
  float pv[4][4];
  #pragma unroll
  for (int mi=0;mi<4;mi++) {
    #pragma unroll
    for (int r=0;r<4;r++) {
      int e = row0 + wm*64 + mi*16 + quad*4 + r;
      int s = ei[e], d = ei[N_EDGES + e];
      const unsigned short* xlr = xl_bf + (size_t)s*1024;
      const unsigned short* xrr = xr_bf + (size_t)d*1024;
      float p = 0.f;
      #pragma unroll
      for (int ni=0;ni<4;ni++) {
        int col = col0 + wn*64 + ni*16 + l16;
        float z = acc[mi][ni][r] + bf2f(xlr[col]) + bf2f(xrr[col]);
        z = leaky02(z);
        p += z*att4[ni];
      }
      p += __shfl_down(p, 8, 16);
      p += __shfl_down(p, 4, 16);
      p += __shfl_down(p, 2, 16);
      p += __shfl_down(p, 1, 16);
      pv[mi][r] = p;
    }
  }
  if (wn == 1 && l16 == 0) {
    #pragma unroll
    for (int mi=0;mi<4;mi++)
      #pragma unroll
      for (int r=0;r<4;r++)
        tmp[wm*64 + mi*16 + quad*4 + r] = pv[mi][r];
  }
  __syncthreads();
  if (wn == 0 && l16 == 0) {
    #pragma unroll
    for (int mi=0;mi<4;mi++)
      #pragma unroll
      for (int r=0;r<4;r++) {
        int le = wm*64 + mi*16 + quad*4 + r;
        logit_part[(size_t)(row0 + le)*8 + by] = pv[mi][r] + tmp[le];
      }
  }
}

// ---------------- fused softmax + GAT aggregation: WAVE per node ----------------
// 4 nodes/block, no __syncthreads. Lane owns 16 cols. XCD swizzle: 4 graphs/XCD.
__global__ __launch_bounds__(256) void k_softmax_gat(
    const int* __restrict__ ei, const int* __restrict__ rowptr, const int* __restrict__ csr,
    const float* __restrict__ logit_part,
    const unsigned short* __restrict__ xl_bf, const unsigned short* __restrict__ xr_bf,
    const float* __restrict__ we_loop, const float* __restrict__ att,
    const float* __restrict__ bgat,
    float* __restrict__ alpha, unsigned short* __restrict__ gat_bf) {
  int blk = blockIdx.x;                         // 4096
  int wid = threadIdx.x >> 6, lane = threadIdx.x & 63;
  int n = ((blk & 7) << 11) + ((blk >> 3) << 2) + wid;
  int c0 = lane*16;

  // --- self-loop logit: dot over this lane's 16 cols, then 64-lane butterfly ---
  float sll;
  {
    const uint4* xp = (const uint4*)(xl_bf + (size_t)n*1024 + c0);
    const uint4* rp = (const uint4*)(xr_bf + (size_t)n*1024 + c0);
    uint4 xa0 = xp[0], xa1 = xp[1];
    uint4 xb0 = rp[0], xb1 = rp[1];
    const unsigned short* ua = (const unsigned short*)&xa0;   // 8+8 via two ptrs
    const unsigned short* ub = (const unsigned short*)&xb0;
    const unsigned short* ua1 = (const unsigned short*)&xa1;
    const unsigned short* ub1 = (const unsigned short*)&xb1;
    float s = 0.f;
    #pragma unroll
    for (int j=0;j<8;j++) {
      float z = bf2f(ua[j]) + bf2f(ub[j]) + we_loop[c0+j];
      s += leaky02(z) * att[c0+j];
    }
    #pragma unroll
    for (int j=0;j<8;j++) {
      float z = bf2f(ua1[j]) + bf2f(ub1[j]) + we_loop[c0+8+j];
      s += leaky02(z) * att[c0+8+j];
    }
    #pragma unroll
    for (int m=1; m<64; m<<=1) s += __shfl_xor(s, m);
    sll = s;
  }

  int beg = rowptr[n], end = rowptr[n+1];
  // --- pass 1: max logit ---
  float mx = -1e30f;
  for (int p = beg + lane; p < end; p += 64) {
    int e = csr[p];
    float lg;
    if (e < N_EDGES) {
      const float4* lp = (const float4*)(logit_part + (size_t)e*8);
      float4 q0 = lp[0], q1 = lp[1];
      lg = q0.x+q0.y+q0.z+q0.w+q1.x+q1.y+q1.z+q1.w;
    } else lg = sll;
    mx = fmaxf(mx, lg);
  }
  #pragma unroll
  for (int m=1; m<64; m<<=1) mx = fmaxf(mx, __shfl_xor(mx, m));
  // --- pass 2: sum of exp ---
  float ss = 0.f;
  for (int p = beg + lane; p < end; p += 64) {
    int e = csr[p];
    float lg;
    if (e < N_EDGES) {
      const float4* lp = (const float4*)(logit_part + (size_t)e*8);
      float4 q0 = lp[0], q1 = lp[1];
      lg = q0.x+q0.y+q0.z+q0.w+q1.x+q1.y+q1.z+q1.w;
    } else lg = sll;
    ss += expf(lg - mx);
  }
  #pragma unroll
  for (int m=1; m<64; m<<=1) ss += __shfl_xor(ss, m);
  float inv = 1.f/(ss + 1e-16f);

  // --- pass 3: alpha write + aggregation (chunks of 64 edges) ---
  float acc[16];
  {
    const float4* bp = (const float4*)(bgat + c0);
    float4 b0 = bp[0], b1 = bp[1], b2 = bp[2], b3 = bp[3];
    acc[0]=b0.x; acc[1]=b0.y; acc[2]=b0.z; acc[3]=b0.w;
    acc[4]=b1.x; acc[5]=b1.y; acc[6]=b1.z; acc[7]=b1.w;
    acc[8]=b2.x; acc[9]=b2.y; acc[10]=b2.z; acc[11]=b2.w;
    acc[12]=b3.x; acc[13]=b3.y; acc[14]=b3.z; acc[15]=b3.w;
  }
  for (int p0 = beg; p0 < end; p0 += 64) {
    int p = p0 + lane;
    float a = 0.f; int src = 0;
    if (p < end) {
      int e = csr[p];
      float lg;
      if (e < N_EDGES) {
        const float4* lp = (const float4*)(logit_part + (size_t)e*8);
        float4 q0 = lp[0], q1 = lp[1];
        lg = q0.x+q0.y+q0.z+q0.w+q1.x+q1.y+q1.z+q1.w;
        src = ei[e];
      } else { lg = sll; src = e - N_EDGES; }
      a = expf(lg - mx)*inv;
      alpha[e] = a;
    }
    int kmax = end - p0; if (kmax > 64) kmax = 64;
    for (int q = 0; q < kmax; q++) {
      float aq = __shfl(a, q);
      int sq = __shfl(src, q);
      const uint4* xp = (const uint4*)(xl_bf + (size_t)sq*1024 + c0);
      uint4 u0 = xp[0], u1 = xp[1];
      const unsigned short* uu0 = (const unsigned short*)&u0;
      const unsigned short* uu1 = (const unsigned short*)&u1;
      #pragma unroll
      for (int j=0;j<8;j++) acc[j]   += aq * bf2f(uu0[j]);
      #pragma unroll
      for (int j=0;j<8;j++) acc[8+j] += aq * bf2f(uu1[j]);
    }
  }
  // --- write gat row (32B/lane) ---
  unsigned short o[16];
  #pragma unroll
  for (int j=0;j<16;j++) o[j] = f2bf(acc[j]);
  uint4* gp = (uint4*)(gat_bf + (size_t)n*1024 + c0);
  gp[0] = *(const uint4*)&o[0];
  gp[1] = *(const uint4*)&o[8];
}

// ---------------- per-graph weighted sums of gat (512 blocks, ushort4) ----------------
// grid (32, 16): y = node chunk of 32
__global__ __launch_bounds__(256) void k_nodepool(
    const unsigned short* __restrict__ gat_bf, const int* __restrict__ odeg,
    const int* __restrict__ rowptr,
    float* __restrict__ P_G, float* __restrict__ P_DG, float* __restrict__ P_gat) {
  int b = blockIdx.x, nc = blockIdx.y;
  int c4 = threadIdx.x;                 // cols c4*4 .. c4*4+3
  float a1[4]={0,0,0,0}, a2[4]={0,0,0,0}, a3[4]={0,0,0,0};
  int n0 = b*512 + nc*32;
  for (int i=0;i<32;i++){
    int n = n0 + i;
    ushort4 g4 = ((const ushort4*)(gat_bf + (size_t)n*1024))[c4];
    float od = (float)odeg[n];
    float dg = (float)(rowptr[n+1]-rowptr[n]);
    float g0 = bf2f(g4.x), g1 = bf2f(g4.y), g2 = bf2f(g4.z), g3 = bf2f(g4.w);
    a1[0]+=od*g0; a1[1]+=od*g1; a1[2]+=od*g2; a1[3]+=od*g3;
    a2[0]+=dg*g0; a2[1]+=dg*g1; a2[2]+=dg*g2; a2[3]+=dg*g3;
    a3[0]+=g0; a3[1]+=g1; a3[2]+=g2; a3[3]+=g3;
  }
  #pragma unroll
  for (int j=0;j<4;j++){
    atomicAdd(&P_G [b*1024 + c4*4+j], a1[j]);
    atomicAdd(&P_DG[b*1024 + c4*4+j], a2[j]);
    atomicAdd(&P_gat[b*1024 + c4*4+j], a3[j]);
  }
}

// ---------------- edge pooling ----------------
__global__ __launch_bounds__(256) void k_edgepool(
    const float* __restrict__ ea, const float* __restrict__ We, const float* __restrict__ be,
    const float* __restrict__ alpha, float* __restrict__ P_S, float* __restrict__ pe) {
  __shared__ float sea[640];
  __shared__ float sal[128];
  int b = blockIdx.x, chy = blockIdx.y, tid = threadIdx.x;
  int mode = (chy < 20) ? 0 : 1;
  int ch = (chy < 20) ? chy : (chy - 20);
  int c1 = tid, c2 = tid + 256;
  bool v2 = (c2 < 511);
  float w1[5], w2[5]={0,0,0,0,0}, b1v, b2v=0.f;
  #pragma unroll
  for (int q=0;q<5;q++) w1[q] = We[c1*5+q];
  b1v = be[c1];
  if (v2) {
    #pragma unroll
    for (int q=0;q<5;q++) w2[q] = We[c2*5+q];
    b2v = be[c2];
  }
  int base = (mode == 0)
    ? ((ch < 16) ? (b*2048 + ch*128) : (N_EDGES + b*512 + (ch-16)*128))
    : (b*2560 + ch*128);
  for (int i=tid;i<640;i+=256){
    int r = base + i/5;
    sea[i] = (r < N_EDGES) ? ea[(size_t)r*5 + (i%5)] : 1.0f;
  }
  for (int i=tid;i<128;i+=256) sal[i] = alpha[base + i];
  __syncthreads();
  float acc1 = 0.f, acc2 = 0.f;
  for (int rr=0; rr<128; rr++) {
    const float* er = &sea[rr*5];
    acc1 += leaky01(b1v + er[0]*w1[0]+er[1]*w1[1]+er[2]*w1[2]+er[3]*w1[3]+er[4]*w1[4]);
    if (v2) acc2 += leaky01(b2v + er[0]*w2[0]+er[1]*w2[1]+er[2]*w2[2]+er[3]*w2[3]+er[4]*w2[4]);
    else    acc2 += sal[rr];
  }
  if (mode == 0) {
    atomicAdd(&P_S[b*512+c1], acc1);
    atomicAdd(&P_S[b*512+c2], acc2);
  } else {
    const float sc = 1.f/2560.f;
    atomicAdd(&pe[b*512+c1], acc1*sc);
    atomicAdd(&pe[b*512+c2], acc2*sc);
  }
}

// ---------------- pn via tiny fused GEMMs (XCD-swizzled) ----------------
__global__ __launch_bounds__(256) void k_pn(
    const float* __restrict__ P_G, const float* __restrict__ P_DG,
    const float* __restrict__ P_S, const float* __restrict__ P_gat,
    const float* __restrict__ Wm, const float* __restrict__ bm,
    const float* __restrict__ Wmi, const float* __restrict__ bmi,
    const float* __restrict__ Wce, const float* __restrict__ bce,
    float* __restrict__ pn) {
  __shared__ float sPg[1024], sPdg[1024], sPs[512];
  int blk = blockIdx.x;
  int xcd = blk & 7, slot = blk >> 3;
  int colgrp = xcd*2 + (slot & 1);
  int b = slot >> 1;
  int col0 = colgrp*64;
  int tid = threadIdx.x, w = tid >> 6, lane = tid & 63;
  for (int i=tid;i<1024;i+=256){ sPg[i]=P_G[b*1024+i]; sPdg[i]=P_DG[b*1024+i]; }
  for (int i=tid;i<512;i+=256) sPs[i]=P_S[b*512+i];
  __syncthreads();
  for (int c=0;c<16;c++){
    int j = col0 + w*16 + c;
    const float* wm  = Wm  + (size_t)j*1024;
    const float* wmi = Wmi + (size_t)j*1024;
    const float* wce = Wce + (size_t)j*512;
    float s = 0.f;
    #pragma unroll 4
    for (int i=0;i<16;i++){ int k = lane + i*64; s += sPg[k]*wm[k] + sPdg[k]*wmi[k]; }
    #pragma unroll 4
    for (int i=0;i<8;i++){ int k = lane + i*64; s += sPs[k]*wce[k]; }
    #pragma unroll
    for (int off=32; off; off>>=1) s += __shfl_down(s, off);
    if (lane == 0) {
      pn[b*1024+j] = (s + P_gat[b*1024+j] + 2560.f*(bm[j]+bmi[j]+bce[j])) * (1.f/512.f);
    }
  }
}

// ---------------- final head ----------------
__global__ __launch_bounds__(256) void k_final(
    const float* __restrict__ pn, const float* __restrict__ pe, const float* __restrict__ yg,
    const float* __restrict__ W1, const float* __restrict__ b1,
    const float* __restrict__ W2, const float* __restrict__ b2,
    float* __restrict__ out) {
  __shared__ float pooled[2048];
  __shared__ float red[256];
  int b = blockIdx.x, tid = threadIdx.x;
  for (int i=tid;i<1024;i+=256) pooled[i]      = pn[b*1024+i];
  for (int i=tid;i<512;i+=256)  pooled[1024+i] = pe[b*512+i];
  for (int i=tid;i<512;i+=256)  pooled[1536+i] = yg[b*512+i];
  __syncthreads();
  const float4* w4 = (const float4*)(W1 + (size_t)tid*2048);
  const float4* p4 = (const float4*)pooled;
  float s = b1[tid];
  for (int k=0;k<512;k++){
    float4 w = w4[k]; float4 p = p4[k];
    s += w.x*p.x + w.y*p.y + w.z*p.z + w.w*p.w;
  }
  s = leaky01(s);
  red[tid] = s * W2[tid];
  __syncthreads();
  for (int off=128; off; off>>=1){
    if (tid < off) red[tid] += red[tid+off];
    __syncthreads();
  }
  if (tid == 0){
    float o = red[0] + b2[0];
    out[b] = 1.f/(1.f+expf(-o));
  }
}

// ---------------- launcher ----------------
extern "C" void kernel_launch(void* const* d_in, const int* in_sizes, int n_in,
                              void* d_out, int out_size, void* d_ws, size_t ws_size,
                              hipStream_t stream) {
  const float* x   = (const float*)d_in[0];
  const int*   ei  = (const int*)  d_in[1];
  const float* ea  = (const float*)d_in[2];
  const float* y   = (const float*)d_in[3];
  const float* Wn  = (const float*)d_in[5];
  const float* bn  = (const float*)d_in[6];
  const float* We  = (const float*)d_in[7];
  const float* be  = (const float*)d_in[8];
  const float* Wg  = (const float*)d_in[9];
  const float* bg  = (const float*)d_in[10];
  const float* Wl  = (const float*)d_in[11];
  const float* bl  = (const float*)d_in[12];
  const float* Wr  = (const float*)d_in[13];
  const float* br  = (const float*)d_in[14];
  const float* Wge = (const float*)d_in[15];
  const float* att = (const float*)d_in[16];
  const float* bgat= (const float*)d_in[17];
  const float* Wm  = (const float*)d_in[18];
  const float* bm  = (const float*)d_in[19];
  const float* Wmi = (const float*)d_in[20];
  const float* bmi = (const float*)d_in[21];
  const float* Wce = (const float*)d_in[22];
  const float* bce = (const float*)d_in[23];
  const float* W1  = (const float*)d_in[24];
  const float* b1  = (const float*)d_in[25];
  const float* W2  = (const float*)d_in[26];
  const float* b2  = (const float*)d_in[27];
  float* out = (float*)d_out;

  char* ws = (char*)d_ws;
  unsigned short* xl_bf  = (unsigned short*)(ws + OFF_XL);
  unsigned short* xr_bf  = (unsigned short*)(ws + OFF_XR);
  unsigned short* gat_bf = (unsigned short*)(ws + OFF_XR);   // alias
  unsigned short* E_bf   = (unsigned short*)(ws + OFF_EBF);
  unsigned short* h_bf   = (unsigned short*)(ws + OFF_HBF);
  unsigned short* Wcat   = (unsigned short*)(ws + OFF_WCAT);
  unsigned short* Wge_p  = (unsigned short*)(ws + OFF_WGEP);
  float* lpart  = (float*)(ws + OFF_LPART);
  float* zone   = (float*)(ws + OFF_DEG);
  int*   deg    = (int*)  (ws + OFF_DEG);
  int*   odeg   = (int*)  (ws + OFF_ODEG);
  int*   cursor = (int*)  (ws + OFF_CURS);
  float* P_G    = (float*)(ws + OFF_PG);
  float* P_DG   = (float*)(ws + OFF_PDG);
  float* P_gat  = (float*)(ws + OFF_PGAT);
  float* P_S    = (float*)(ws + OFF_PS);
  float* pe     = (float*)(ws + OFF_PE);
  int*   rowptr = (int*)  (ws + OFF_ROWP);
  int*   csr    = (int*)  (ws + OFF_CSR);
  float* alpha  = (float*)(ws + OFF_ALPHA);
  float* we_loop= (float*)(ws + OFF_WLOOP);
  float* yg     = (float*)(ws + OFF_YG);
  float* pn     = (float*)(ws + OFF_PN);

  k_prep0<<<dim3(4340), dim3(256), 0, stream>>>(x, Wn, bn, Wl, Wr, Wge, y, Wg, bg, We, be,
                                                zone, h_bf, Wcat, Wge_p, yg, we_loop);
  k_gemm_xlxr<<<dim3(2048), dim3(256), 0, stream>>>(h_bf, Wcat, bl, br, xl_bf, xr_bf);
  k_prep_e<<<dim3(16704), dim3(256), 0, stream>>>(ea, We, be, E_bf, ei, deg, odeg);
  k_mfma_we<<<dim3(4096), dim3(256), 0, stream>>>(E_bf, Wge_p, ei, xl_bf, xr_bf, att, lpart);
  k_scan<<<dim3(1), dim3(1024), 0, stream>>>(deg, rowptr);
  k_fill_csr<<<dim3(320), dim3(256), 0, stream>>>(ei, rowptr, cursor, csr);
  k_softmax_gat<<<dim3(4096), dim3(256), 0, stream>>>(ei, rowptr, csr, lpart, xl_bf, xr_bf,
                                                      we_loop, att, bgat, alpha, gat_bf);
  k_nodepool<<<dim3(32,16), dim3(256), 0, stream>>>(gat_bf, odeg, rowptr, P_G, P_DG, P_gat);
  k_edgepool<<<dim3(32,40), dim3(256), 0, stream>>>(ea, We, be, alpha, P_S, pe);
  k_pn<<<dim3(512), dim3(256), 0, stream>>>(P_G, P_DG, P_S, P_gat, Wm, bm, Wmi, bmi, Wce, bce, pn);
  k_final<<<dim3(32), dim3(256), 0, stream>>>(pn, pe, yg, W1, b1, W2, b2, out);
}

// Round 12
// 544.310 us; speedup vs baseline: 1.3482x; 1.1502x over previous
//
#include <hip/hip_runtime.h>
#include <cstdint>
#include <cstddef>

#define N_NODES 16384
#define N_EDGES 65536
#define ETOT    81920
#define B_GR    32

typedef __attribute__((ext_vector_type(8))) short bf16x8;
typedef __attribute__((ext_vector_type(4))) float f32x4;

// ---------------- workspace layout (bytes), peak 138,285,184 ----------------
static constexpr size_t OFF_XL    = 0;              // 33,554,432
static constexpr size_t OFF_XR    = 33554432ULL;    // 33,554,432 (gat_bf aliases)
static constexpr size_t OFF_EBF   = 67108864ULL;    // 67,108,864  E_bf
static constexpr size_t OFF_HBF   = 67108864ULL;    //   alias: h_bf (dead after xlxr GEMM)
static constexpr size_t OFF_WCAT  = 83886080ULL;    //   alias: Wcat (dead after xlxr GEMM)
static constexpr size_t OFF_ROWP  = 67108864ULL;    //   alias: rowptr (after k_mfma_we)
static constexpr size_t OFF_CSR   = 67174656ULL;    //   alias
static constexpr size_t OFF_ALPHA = 67502336ULL;    //   alias
static constexpr size_t OFF_WGEP  = 134217728ULL;   // 1,048,576
static constexpr size_t OFF_LPART = 135266304ULL;   // 2,097,152  logit_part [65536x8 f32]
// ---- zero zone (720,896 B) ----
static constexpr size_t OFF_DEG   = 137363456ULL;
static constexpr size_t OFF_ODEG  = 137428992ULL;
static constexpr size_t OFF_CURS  = 137494528ULL;
static constexpr size_t OFF_PG    = 137560064ULL;
static constexpr size_t OFF_PDG   = 137691136ULL;
static constexpr size_t OFF_PGAT  = 137822208ULL;
static constexpr size_t OFF_PS    = 137953280ULL;
static constexpr size_t OFF_PE    = 138018816ULL;
// ---- end zero zone ----
static constexpr size_t OFF_WLOOP = 138084352ULL;
static constexpr size_t OFF_YG    = 138088448ULL;
static constexpr size_t OFF_PN    = 138153984ULL;
static constexpr size_t OFF_OPRE  = 138285056ULL;   // 128 (zeroed in k_pn)
// end = 138,285,184

__device__ __forceinline__ float leaky01(float v){ return v >= 0.f ? v : 0.01f*v; }
__device__ __forceinline__ float leaky02(float v){ return v >= 0.f ? v : 0.2f*v; }
__device__ __forceinline__ unsigned short f2bf(float f){
  union { float f; unsigned u; } v; v.f = f;
  unsigned r = v.u + 0x7FFFu + ((v.u >> 16) & 1u);
  return (unsigned short)(r >> 16);
}
__device__ __forceinline__ float bf2f(unsigned short h){
  union { unsigned u; float f; } v; v.u = ((unsigned)h) << 16;
  return v.f;
}

// ---------------- merged prep ----------------
__global__ __launch_bounds__(256) void k_prep0(
    const float* __restrict__ x, const float* __restrict__ Wn, const float* __restrict__ bn,
    const float* __restrict__ Wl, const float* __restrict__ Wr,
    const float* __restrict__ Wge, const float* __restrict__ y,
    const float* __restrict__ Wg, const float* __restrict__ bg,
    const float* __restrict__ We, const float* __restrict__ be,
    float* __restrict__ zone, unsigned short* __restrict__ h_bf,
    unsigned short* __restrict__ Wcat, unsigned short* __restrict__ Wge_p,
    float* __restrict__ yg, float* __restrict__ we_loop) {
  __shared__ float e_lds[512];
  int bx = blockIdx.x, tid = threadIdx.x;
  if (bx < 176) {
    ((float4*)zone)[bx*256 + tid] = (float4){0.f,0.f,0.f,0.f};
  } else if (bx < 1200) {               // h_bf
    int gid = (bx-176)*256 + tid;
    int base = gid*8;
    int n = base >> 9, j = base & 511;
    float xv = x[n];
    float4 w0 = *(const float4*)(Wn + j);
    float4 w1 = *(const float4*)(Wn + j + 4);
    float4 b0 = *(const float4*)(bn + j);
    float4 b1 = *(const float4*)(bn + j + 4);
    unsigned short o[8];
    o[0]=f2bf(leaky01(xv*w0.x+b0.x)); o[1]=f2bf(leaky01(xv*w0.y+b0.y));
    o[2]=f2bf(leaky01(xv*w0.z+b0.z)); o[3]=f2bf(leaky01(xv*w0.w+b0.w));
    o[4]=f2bf(leaky01(xv*w1.x+b1.x)); o[5]=f2bf(leaky01(xv*w1.y+b1.y));
    o[6]=f2bf(leaky01(xv*w1.z+b1.z)); o[7]=f2bf(leaky01(xv*w1.w+b1.w));
    ((uint4*)h_bf)[gid] = *(const uint4*)o;
  } else if (bx < 2224) {               // Wcat
    int i = (bx-1200)*256 + tid;
    int base = i*4;
    const float* src = (base < 524288) ? (Wl + base) : (Wr + base - 524288);
    float4 v = *(const float4*)src;
    ushort4 o; o.x=f2bf(v.x); o.y=f2bf(v.y); o.z=f2bf(v.z); o.w=f2bf(v.w);
    ((ushort4*)Wcat)[i] = o;
  } else if (bx < 4272) {               // Wge_p
    int gid = (bx-2224)*256 + tid;
    int j = gid >> 9, k = gid & 511;
    Wge_p[gid] = (k < 511) ? f2bf(Wge[(size_t)j*511 + k]) : (unsigned short)0;
  } else if (bx < 4336) {               // yg
    int gid = (bx-4272)*256 + tid;
    int b = gid >> 9, j = gid & 511;
    float s = bg[j];
    #pragma unroll
    for (int k=0;k<5;k++) s += y[b*5+k]*Wg[j*5+k];
    yg[gid] = leaky01(s);
  } else {                              // we_loop
    for (int c = tid; c < 512; c += 256) {
      float v = 0.f;
      if (c < 511) {
        float s = be[c];
        #pragma unroll
        for (int q=0;q<5;q++) s += We[c*5+q];
        v = leaky01(s);
      }
      e_lds[c] = v;
    }
    __syncthreads();
    int j = (bx-4336)*256 + tid;
    float s = 0.f;
    for (int k=0;k<511;k++) s += e_lds[k]*Wge[(size_t)j*511+k];
    we_loop[j] = s;
  }
}

// ---------------- E_bf prep + degree counts (merged) ----------------
__global__ __launch_bounds__(256) void k_prep_e(
    const float* __restrict__ ea, const float* __restrict__ We, const float* __restrict__ be,
    unsigned short* __restrict__ E_bf,
    const int* __restrict__ ei, int* __restrict__ deg, int* __restrict__ odeg) {
  int blk = blockIdx.x;
  if (blk < 16384) {
    int gid = blk*256 + threadIdx.x;
    int e = gid >> 6, cg = gid & 63;
    int c0 = cg*8;
    const float* e5 = ea + (size_t)e*5;
    float a0=e5[0], a1=e5[1], a2=e5[2], a3=e5[3], a4=e5[4];
    unsigned short o[8];
    #pragma unroll
    for (int j=0;j<8;j++) {
      int c = c0 + j;
      float v = 0.f;
      if (c < 511) {
        const float* w = We + c*5;
        float s = be[c] + a0*w[0] + a1*w[1] + a2*w[2] + a3*w[3] + a4*w[4];
        v = leaky01(s);
      }
      o[j] = f2bf(v);
    }
    ((uint4*)E_bf)[gid] = *(const uint4*)o;
  } else {
    int i = (blk-16384)*256 + threadIdx.x;
    int s, d;
    if (i < N_EDGES) { s = ei[i]; d = ei[N_EDGES + i]; }
    else { s = i - N_EDGES; d = s; }
    atomicAdd(&deg[d], 1);
    atomicAdd(&odeg[s], 1);
  }
}

// ---------------- CSR build ----------------
__global__ __launch_bounds__(1024) void k_scan(const int* __restrict__ deg, int* __restrict__ rowptr) {
  __shared__ int sums[1024];
  int t = threadIdx.x;
  int local[16]; int s = 0;
  #pragma unroll
  for (int i=0;i<16;i++){ local[i] = deg[t*16+i]; s += local[i]; }
  sums[t] = s; __syncthreads();
  for (int off=1; off<1024; off<<=1) {
    int v = (t >= off) ? sums[t-off] : 0;
    __syncthreads();
    sums[t] += v;
    __syncthreads();
  }
  int run = (t==0) ? 0 : sums[t-1];
  if (t==0) rowptr[0] = 0;
  #pragma unroll
  for (int i=0;i<16;i++){ run += local[i]; rowptr[t*16+i+1] = run; }
}

__global__ void k_fill_csr(const int* __restrict__ ei, const int* __restrict__ rowptr,
                           int* __restrict__ cursor, int* __restrict__ csr) {
  int i = blockIdx.x*blockDim.x + threadIdx.x;
  int d = (i < N_EDGES) ? ei[N_EDGES + i] : (i - N_EDGES);
  int pos = rowptr[d] + atomicAdd(&cursor[d], 1);
  csr[pos] = i;
}

// ================= double-buffered MFMA GEMM core (R7, proven) =================

// ---------------- combined xl/xr MFMA GEMM ----------------
__global__ __launch_bounds__(256) void k_gemm_xlxr(
    const unsigned short* __restrict__ h_bf, const unsigned short* __restrict__ Wcat,
    const float* __restrict__ bl, const float* __restrict__ br,
    unsigned short* __restrict__ xl_bf, unsigned short* __restrict__ xr_bf) {
  __shared__ unsigned short As[2][4096];
  __shared__ unsigned short Bs[2][4096];
  int blk = blockIdx.x;
  int xcd = blk & 7, slot = blk >> 3;
  int bx = xcd*16 + (slot >> 4), by = slot & 15;
  int row0 = bx*128, col0 = by*128;
  int tid = threadIdx.x;
  int w = tid >> 6, lane = tid & 63;
  int wm = w >> 1, wn = w & 1;
  int quad = lane >> 4, l16 = lane & 15;
  int ldoff = w*512 + lane*8;
  const unsigned short* gA = h_bf + (size_t)(row0 + w*16 + l16)*512 + quad*8;
  const unsigned short* gB = Wcat + (size_t)(col0 + w*16 + l16)*512 + quad*8;
  f32x4 acc[4][4];
  #pragma unroll
  for (int i=0;i<4;i++)
    #pragma unroll
    for (int j=0;j<4;j++) acc[i][j] = (f32x4){0.f,0.f,0.f,0.f};

  {
    uint4 a0 = *(const uint4*)(gA);
    uint4 a1 = *(const uint4*)(gA + 32768);
    uint4 b0 = *(const uint4*)(gB);
    uint4 b1 = *(const uint4*)(gB + 32768);
    *(uint4*)&As[0][ldoff] = a0; *(uint4*)&As[0][2048+ldoff] = a1;
    *(uint4*)&Bs[0][ldoff] = b0; *(uint4*)&Bs[0][2048+ldoff] = b1;
  }
  __syncthreads();
  int cur = 0;
  #pragma unroll 2
  for (int k0 = 32; k0 <= 512; k0 += 32) {
    uint4 na0, na1, nb0, nb1;
    bool more = (k0 < 512);
    if (more) {
      na0 = *(const uint4*)(gA + k0);
      na1 = *(const uint4*)(gA + 32768 + k0);
      nb0 = *(const uint4*)(gB + k0);
      nb1 = *(const uint4*)(gB + 32768 + k0);
    }
    bf16x8 af[4], bfr[4];
    #pragma unroll
    for (int mi=0;mi<4;mi++)
      af[mi] = *(const bf16x8*)&As[cur][(wm*4+mi)*512 + quad*128 + l16*8];
    #pragma unroll
    for (int ni=0;ni<4;ni++)
      bfr[ni] = *(const bf16x8*)&Bs[cur][(wn*4+ni)*512 + quad*128 + l16*8];
    #pragma unroll
    for (int mi=0;mi<4;mi++)
      #pragma unroll
      for (int ni=0;ni<4;ni++)
        acc[mi][ni] = __builtin_amdgcn_mfma_f32_16x16x32_bf16(af[mi], bfr[ni], acc[mi][ni], 0, 0, 0);
    if (more) {
      *(uint4*)&As[cur^1][ldoff] = na0; *(uint4*)&As[cur^1][2048+ldoff] = na1;
      *(uint4*)&Bs[cur^1][ldoff] = nb0; *(uint4*)&Bs[cur^1][2048+ldoff] = nb1;
    }
    __syncthreads();
    cur ^= 1;
  }
  bool isL = (by < 8);
  const float* bias = isL ? bl : br;
  unsigned short* O = isL ? xl_bf : xr_bf;
  int cb = isL ? col0 : (col0 - 1024);
  float bias4[4];
  #pragma unroll
  for (int ni=0;ni<4;ni++) bias4[ni] = bias[cb + wn*64 + ni*16 + l16];
  #pragma unroll
  for (int mi=0;mi<4;mi++)
    #pragma unroll
    for (int ni=0;ni<4;ni++) {
      int col = cb + wn*64 + ni*16 + l16;
      #pragma unroll
      for (int r=0;r<4;r++) {
        int row = row0 + wm*64 + mi*16 + quad*4 + r;
        O[(size_t)row*1024 + col] = f2bf(acc[mi][ni][r] + bias4[ni]);
      }
    }
}

// ---------------- we-GEMM + fused attention logits (exact R7 form) ----------------
__global__ __launch_bounds__(256) void k_mfma_we(
    const unsigned short* __restrict__ E_bf, const unsigned short* __restrict__ Wge_bf,
    const int* __restrict__ ei,
    const unsigned short* __restrict__ xl_bf, const unsigned short* __restrict__ xr_bf,
    const float* __restrict__ att, float* __restrict__ logit_part) {
  __shared__ unsigned short As[2][4096];
  __shared__ unsigned short Bs[2][4096];
  __shared__ float tmp[128];
  int blk = blockIdx.x;
  int xcd = blk & 7, slot = blk >> 3;
  int bx = xcd*64 + (slot >> 3), by = slot & 7;
  int row0 = bx*128, col0 = by*128;
  int tid = threadIdx.x;
  int w = tid >> 6, lane = tid & 63;
  int wm = w >> 1, wn = w & 1;
  int quad = lane >> 4, l16 = lane & 15;
  int ldoff = w*512 + lane*8;
  const unsigned short* gA = E_bf  + (size_t)(row0 + w*16 + l16)*512 + quad*8;
  const unsigned short* gB = Wge_bf + (size_t)(col0 + w*16 + l16)*512 + quad*8;
  f32x4 acc[4][4];
  #pragma unroll
  for (int i=0;i<4;i++)
    #pragma unroll
    for (int j=0;j<4;j++) acc[i][j] = (f32x4){0.f,0.f,0.f,0.f};

  {
    uint4 a0 = *(const uint4*)(gA);
    uint4 a1 = *(const uint4*)(gA + 32768);
    uint4 b0 = *(const uint4*)(gB);
    uint4 b1 = *(const uint4*)(gB + 32768);
    *(uint4*)&As[0][ldoff] = a0; *(uint4*)&As[0][2048+ldoff] = a1;
    *(uint4*)&Bs[0][ldoff] = b0; *(uint4*)&Bs[0][2048+ldoff] = b1;
  }
  __syncthreads();
  int cur = 0;
  #pragma unroll 2
  for (int k0 = 32; k0 <= 512; k0 += 32) {
    uint4 na0, na1, nb0, nb1;
    bool more = (k0 < 512);
    if (more) {
      na0 = *(const uint4*)(gA + k0);
      na1 = *(const uint4*)(gA + 32768 + k0);
      nb0 = *(const uint4*)(gB + k0);
      nb1 = *(const uint4*)(gB + 32768 + k0);
    }
    bf16x8 af[4], bfr[4];
    #pragma unroll
    for (int mi=0;mi<4;mi++)
      af[mi] = *(const bf16x8*)&As[cur][(wm*4+mi)*512 + quad*128 + l16*8];
    #pragma unroll
    for (int ni=0;ni<4;ni++)
      bfr[ni] = *(const bf16x8*)&Bs[cur][(wn*4+ni)*512 + quad*128 + l16*8];
    #pragma unroll
    for (int mi=0;mi<4;mi++)
      #pragma unroll
      for (int ni=0;ni<4;ni++)
        acc[mi][ni] = __builtin_amdgcn_mfma_f32_16x16x32_bf16(af[mi], bfr[ni], acc[mi][ni], 0, 0, 0);
    if (more) {
      *(uint4*)&As[cur^1][ldoff] = na0; *(uint4*)&As[cur^1][2048+ldoff] = na1;
      *(uint4*)&Bs[cur^1][ldoff] = nb0; *(uint4*)&Bs[cur^1][2048+ldoff] = nb1;
    }
    __syncthreads();
    cur ^= 1;
  }
  float att4[4];
  #pragma unroll
  for (int ni=0;ni<4;ni++) att4[ni] = att[col0 + wn*64 + ni*16 + l16];
  float pv[4][4];
  #pragma unroll
  for (int mi=0;mi<4;mi++) {
    #pragma unroll
    for (int r=0;r<4;r++) {
      int e = row0 + wm*64 + mi*16 + quad*4 + r;
      int s = ei[e], d = ei[N_EDGES + e];
      const unsigned short* xlr = xl_bf + (size_t)s*1024;
      const unsigned short* xrr = xr_bf + (size_t)d*1024;
      float p = 0.f;
      #pragma unroll
      for (int ni=0;ni<4;ni++) {
        int col = col0 + wn*64 + ni*16 + l16;
        float z = acc[mi][ni][r] + bf2f(xlr[col]) + bf2f(xrr[col]);
        z = leaky02(z);
        p += z*att4[ni];
      }
      p += __shfl_down(p, 8, 16);
      p += __shfl_down(p, 4, 16);
      p += __shfl_down(p, 2, 16);
      p += __shfl_down(p, 1, 16);
      pv[mi][r] = p;
    }
  }
  if (wn == 1 && l16 == 0) {
    #pragma unroll
    for (int mi=0;mi<4;mi++)
      #pragma unroll
      for (int r=0;r<4;r++)
        tmp[wm*64 + mi*16 + quad*4 + r] = pv[mi][r];
  }
  __syncthreads();
  if (wn == 0 && l16 == 0) {
    #pragma unroll
    for (int mi=0;mi<4;mi++)
      #pragma unroll
      for (int r=0;r<4;r++) {
        int le = wm*64 + mi*16 + quad*4 + r;
        logit_part[(size_t)(row0 + le)*8 + by] = pv[mi][r] + tmp[le];
      }
  }
}

// ---------------- fused softmax + GAT aggregation: WAVE per node ----------------
__global__ __launch_bounds__(256) void k_softmax_gat(
    const int* __restrict__ ei, const int* __restrict__ rowptr, const int* __restrict__ csr,
    const float* __restrict__ logit_part,
    const unsigned short* __restrict__ xl_bf, const unsigned short* __restrict__ xr_bf,
    const float* __restrict__ we_loop, const float* __restrict__ att,
    const float* __restrict__ bgat,
    float* __restrict__ alpha, unsigned short* __restrict__ gat_bf) {
  int blk = blockIdx.x;                         // 4096
  int wid = threadIdx.x >> 6, lane = threadIdx.x & 63;
  int n = ((blk & 7) << 11) + ((blk >> 3) << 2) + wid;
  int c0 = lane*16;

  float sll;
  {
    const uint4* xp = (const uint4*)(xl_bf + (size_t)n*1024 + c0);
    const uint4* rp = (const uint4*)(xr_bf + (size_t)n*1024 + c0);
    uint4 xa0 = xp[0], xa1 = xp[1];
    uint4 xb0 = rp[0], xb1 = rp[1];
    const unsigned short* ua = (const unsigned short*)&xa0;
    const unsigned short* ub = (const unsigned short*)&xb0;
    const unsigned short* ua1 = (const unsigned short*)&xa1;
    const unsigned short* ub1 = (const unsigned short*)&xb1;
    float s = 0.f;
    #pragma unroll
    for (int j=0;j<8;j++) {
      float z = bf2f(ua[j]) + bf2f(ub[j]) + we_loop[c0+j];
      s += leaky02(z) * att[c0+j];
    }
    #pragma unroll
    for (int j=0;j<8;j++) {
      float z = bf2f(ua1[j]) + bf2f(ub1[j]) + we_loop[c0+8+j];
      s += leaky02(z) * att[c0+8+j];
    }
    #pragma unroll
    for (int m=1; m<64; m<<=1) s += __shfl_xor(s, m);
    sll = s;
  }

  int beg = rowptr[n], end = rowptr[n+1];
  float mx = -1e30f;
  for (int p = beg + lane; p < end; p += 64) {
    int e = csr[p];
    float lg;
    if (e < N_EDGES) {
      const float4* lp = (const float4*)(logit_part + (size_t)e*8);
      float4 q0 = lp[0], q1 = lp[1];
      lg = q0.x+q0.y+q0.z+q0.w+q1.x+q1.y+q1.z+q1.w;
    } else lg = sll;
    mx = fmaxf(mx, lg);
  }
  #pragma unroll
  for (int m=1; m<64; m<<=1) mx = fmaxf(mx, __shfl_xor(mx, m));
  float ss = 0.f;
  for (int p = beg + lane; p < end; p += 64) {
    int e = csr[p];
    float lg;
    if (e < N_EDGES) {
      const float4* lp = (const float4*)(logit_part + (size_t)e*8);
      float4 q0 = lp[0], q1 = lp[1];
      lg = q0.x+q0.y+q0.z+q0.w+q1.x+q1.y+q1.z+q1.w;
    } else lg = sll;
    ss += expf(lg - mx);
  }
  #pragma unroll
  for (int m=1; m<64; m<<=1) ss += __shfl_xor(ss, m);
  float inv = 1.f/(ss + 1e-16f);

  float acc[16];
  {
    const float4* bp = (const float4*)(bgat + c0);
    float4 b0 = bp[0], b1 = bp[1], b2 = bp[2], b3 = bp[3];
    acc[0]=b0.x; acc[1]=b0.y; acc[2]=b0.z; acc[3]=b0.w;
    acc[4]=b1.x; acc[5]=b1.y; acc[6]=b1.z; acc[7]=b1.w;
    acc[8]=b2.x; acc[9]=b2.y; acc[10]=b2.z; acc[11]=b2.w;
    acc[12]=b3.x; acc[13]=b3.y; acc[14]=b3.z; acc[15]=b3.w;
  }
  for (int p0 = beg; p0 < end; p0 += 64) {
    int p = p0 + lane;
    float a = 0.f; int src = 0;
    if (p < end) {
      int e = csr[p];
      float lg;
      if (e < N_EDGES) {
        const float4* lp = (const float4*)(logit_part + (size_t)e*8);
        float4 q0 = lp[0], q1 = lp[1];
        lg = q0.x+q0.y+q0.z+q0.w+q1.x+q1.y+q1.z+q1.w;
        src = ei[e];
      } else { lg = sll; src = e - N_EDGES; }
      a = expf(lg - mx)*inv;
      alpha[e] = a;
    }
    int kmax = end - p0; if (kmax > 64) kmax = 64;
    for (int q = 0; q < kmax; q++) {
      float aq = __shfl(a, q);
      int sq = __shfl(src, q);
      const uint4* xp = (const uint4*)(xl_bf + (size_t)sq*1024 + c0);
      uint4 u0 = xp[0], u1 = xp[1];
      const unsigned short* uu0 = (const unsigned short*)&u0;
      const unsigned short* uu1 = (const unsigned short*)&u1;
      #pragma unroll
      for (int j=0;j<8;j++) acc[j]   += aq * bf2f(uu0[j]);
      #pragma unroll
      for (int j=0;j<8;j++) acc[8+j] += aq * bf2f(uu1[j]);
    }
  }
  unsigned short o[16];
  #pragma unroll
  for (int j=0;j<16;j++) o[j] = f2bf(acc[j]);
  uint4* gp = (uint4*)(gat_bf + (size_t)n*1024 + c0);
  gp[0] = *(const uint4*)&o[0];
  gp[1] = *(const uint4*)&o[8];
}

// ---------------- merged pooling: nodepool (slots 0..511) + edgepool (512..1791) ----------------
__global__ __launch_bounds__(256) void k_pool(
    const unsigned short* __restrict__ gat_bf, const int* __restrict__ odeg,
    const int* __restrict__ rowptr,
    float* __restrict__ P_G, float* __restrict__ P_DG, float* __restrict__ P_gat,
    const float* __restrict__ ea, const float* __restrict__ We, const float* __restrict__ be,
    const float* __restrict__ alpha, float* __restrict__ P_S, float* __restrict__ pe) {
  __shared__ float sea[640];
  __shared__ float sal[128];
  int slot = blockIdx.x, tid = threadIdx.x;
  if (slot < 512) {
    // ---- nodepool: b=slot>>4, nc=slot&15, 32-node chunk, ushort4 cols ----
    int b = slot >> 4, nc = slot & 15;
    int c4 = tid;
    float a1[4]={0,0,0,0}, a2[4]={0,0,0,0}, a3[4]={0,0,0,0};
    int n0 = b*512 + nc*32;
    for (int i=0;i<32;i++){
      int n = n0 + i;
      ushort4 g4 = ((const ushort4*)(gat_bf + (size_t)n*1024))[c4];
      float od = (float)odeg[n];
      float dg = (float)(rowptr[n+1]-rowptr[n]);
      float g0 = bf2f(g4.x), g1 = bf2f(g4.y), g2 = bf2f(g4.z), g3 = bf2f(g4.w);
      a1[0]+=od*g0; a1[1]+=od*g1; a1[2]+=od*g2; a1[3]+=od*g3;
      a2[0]+=dg*g0; a2[1]+=dg*g1; a2[2]+=dg*g2; a2[3]+=dg*g3;
      a3[0]+=g0; a3[1]+=g1; a3[2]+=g2; a3[3]+=g3;
    }
    #pragma unroll
    for (int j=0;j<4;j++){
      atomicAdd(&P_G [b*1024 + c4*4+j], a1[j]);
      atomicAdd(&P_DG[b*1024 + c4*4+j], a2[j]);
      atomicAdd(&P_gat[b*1024 + c4*4+j], a3[j]);
    }
  } else {
    // ---- edgepool: s = slot-512; b = s&31, chy = s>>5 (0..39) ----
    int s = slot - 512;
    int b = s & 31, chy = s >> 5;
    int mode = (chy < 20) ? 0 : 1;
    int ch = (chy < 20) ? chy : (chy - 20);
    int c1 = tid, c2 = tid + 256;
    bool v2 = (c2 < 511);
    float w1[5], w2[5]={0,0,0,0,0}, b1v, b2v=0.f;
    #pragma unroll
    for (int q=0;q<5;q++) w1[q] = We[c1*5+q];
    b1v = be[c1];
    if (v2) {
      #pragma unroll
      for (int q=0;q<5;q++) w2[q] = We[c2*5+q];
      b2v = be[c2];
    }
    int base = (mode == 0)
      ? ((ch < 16) ? (b*2048 + ch*128) : (N_EDGES + b*512 + (ch-16)*128))
      : (b*2560 + ch*128);
    for (int i=tid;i<640;i+=256){
      int r = base + i/5;
      sea[i] = (r < N_EDGES) ? ea[(size_t)r*5 + (i%5)] : 1.0f;
    }
    for (int i=tid;i<128;i+=256) sal[i] = alpha[base + i];
    __syncthreads();
    float acc1 = 0.f, acc2 = 0.f;
    for (int rr=0; rr<128; rr++) {
      const float* er = &sea[rr*5];
      acc1 += leaky01(b1v + er[0]*w1[0]+er[1]*w1[1]+er[2]*w1[2]+er[3]*w1[3]+er[4]*w1[4]);
      if (v2) acc2 += leaky01(b2v + er[0]*w2[0]+er[1]*w2[1]+er[2]*w2[2]+er[3]*w2[3]+er[4]*w2[4]);
      else    acc2 += sal[rr];
    }
    if (mode == 0) {
      atomicAdd(&P_S[b*512+c1], acc1);
      atomicAdd(&P_S[b*512+c2], acc2);
    } else {
      const float sc = 1.f/2560.f;
      atomicAdd(&pe[b*512+c1], acc1*sc);
      atomicAdd(&pe[b*512+c2], acc2*sc);
    }
  }
}

// ---------------- pn via tiny fused GEMMs (XCD-swizzled) + out_pre zero ----------------
__global__ __launch_bounds__(256) void k_pn(
    const float* __restrict__ P_G, const float* __restrict__ P_DG,
    const float* __restrict__ P_S, const float* __restrict__ P_gat,
    const float* __restrict__ Wm, const float* __restrict__ bm,
    const float* __restrict__ Wmi, const float* __restrict__ bmi,
    const float* __restrict__ Wce, const float* __restrict__ bce,
    float* __restrict__ pn, float* __restrict__ out_pre) {
  __shared__ float sPg[1024], sPdg[1024], sPs[512];
  int blk = blockIdx.x;
  int xcd = blk & 7, slot = blk >> 3;
  int colgrp = xcd*2 + (slot & 1);
  int b = slot >> 1;
  int col0 = colgrp*64;
  int tid = threadIdx.x, w = tid >> 6, lane = tid & 63;
  if (blk == 0 && tid < 32) out_pre[tid] = 0.f;
  for (int i=tid;i<1024;i+=256){ sPg[i]=P_G[b*1024+i]; sPdg[i]=P_DG[b*1024+i]; }
  for (int i=tid;i<512;i+=256) sPs[i]=P_S[b*512+i];
  __syncthreads();
  for (int c=0;c<16;c++){
    int j = col0 + w*16 + c;
    const float* wm  = Wm  + (size_t)j*1024;
    const float* wmi = Wmi + (size_t)j*1024;
    const float* wce = Wce + (size_t)j*512;
    float s = 0.f;
    #pragma unroll 4
    for (int i=0;i<16;i++){ int k = lane + i*64; s += sPg[k]*wm[k] + sPdg[k]*wmi[k]; }
    #pragma unroll 4
    for (int i=0;i<8;i++){ int k = lane + i*64; s += sPs[k]*wce[k]; }
    #pragma unroll
    for (int off=32; off; off>>=1) s += __shfl_down(s, off);
    if (lane == 0) {
      pn[b*1024+j] = (s + P_gat[b*1024+j] + 2560.f*(bm[j]+bmi[j]+bce[j])) * (1.f/512.f);
    }
  }
}

// ---------------- final head: 256 blocks (hc = XCD), partials into out_pre ----------------
__global__ __launch_bounds__(256) void k_final(
    const float* __restrict__ pn, const float* __restrict__ pe, const float* __restrict__ yg,
    const float* __restrict__ W1, const float* __restrict__ b1,
    const float* __restrict__ W2, float* __restrict__ out_pre) {
  __shared__ float pooled[2048];
  int blk = blockIdx.x;
  int hc = blk & 7, b = blk >> 3;      // hc == XCD -> W1 slice L2-resident
  int tid = threadIdx.x;
  for (int i=tid;i<1024;i+=256) pooled[i]      = pn[b*1024+i];
  for (int i=tid;i<512;i+=256)  pooled[1024+i] = pe[b*512+i];
  for (int i=tid;i<512;i+=256)  pooled[1536+i] = yg[b*512+i];
  __syncthreads();
  int r = hc*32 + (tid >> 3);          // hidden row
  int seg = tid & 7;                   // 256-col segment
  const float4* w4 = (const float4*)(W1 + (size_t)r*2048 + seg*256);
  const float4* p4 = (const float4*)(pooled + seg*256);
  float s = 0.f;
  #pragma unroll 8
  for (int k=0;k<64;k++){
    float4 w = w4[k]; float4 p = p4[k];
    s += w.x*p.x + w.y*p.y + w.z*p.z + w.w*p.w;
  }
  s += __shfl_down(s, 4, 8);
  s += __shfl_down(s, 2, 8);
  s += __shfl_down(s, 1, 8);
  if (seg == 0) {
    float h = leaky01(s + b1[r]);
    atomicAdd(&out_pre[b], h * W2[r]);
  }
}

__global__ void k_sigmoid(const float* __restrict__ out_pre, const float* __restrict__ b2,
                          float* __restrict__ out) {
  int b = threadIdx.x;  // 32
  out[b] = 1.f/(1.f + expf(-(out_pre[b] + b2[0])));
}

// ---------------- launcher ----------------
extern "C" void kernel_launch(void* const* d_in, const int* in_sizes, int n_in,
                              void* d_out, int out_size, void* d_ws, size_t ws_size,
                              hipStream_t stream) {
  const float* x   = (const float*)d_in[0];
  const int*   ei  = (const int*)  d_in[1];
  const float* ea  = (const float*)d_in[2];
  const float* y   = (const float*)d_in[3];
  const float* Wn  = (const float*)d_in[5];
  const float* bn  = (const float*)d_in[6];
  const float* We  = (const float*)d_in[7];
  const float* be  = (const float*)d_in[8];
  const float* Wg  = (const float*)d_in[9];
  const float* bg  = (const float*)d_in[10];
  const float* Wl  = (const float*)d_in[11];
  const float* bl  = (const float*)d_in[12];
  const float* Wr  = (const float*)d_in[13];
  const float* br  = (const float*)d_in[14];
  const float* Wge = (const float*)d_in[15];
  const float* att = (const float*)d_in[16];
  const float* bgat= (const float*)d_in[17];
  const float* Wm  = (const float*)d_in[18];
  const float* bm  = (const float*)d_in[19];
  const float* Wmi = (const float*)d_in[20];
  const float* bmi = (const float*)d_in[21];
  const float* Wce = (const float*)d_in[22];
  const float* bce = (const float*)d_in[23];
  const float* W1  = (const float*)d_in[24];
  const float* b1  = (const float*)d_in[25];
  const float* W2  = (const float*)d_in[26];
  const float* b2  = (const float*)d_in[27];
  float* out = (float*)d_out;

  char* ws = (char*)d_ws;
  unsigned short* xl_bf  = (unsigned short*)(ws + OFF_XL);
  unsigned short* xr_bf  = (unsigned short*)(ws + OFF_XR);
  unsigned short* gat_bf = (unsigned short*)(ws + OFF_XR);   // alias
  unsigned short* E_bf   = (unsigned short*)(ws + OFF_EBF);
  unsigned short* h_bf   = (unsigned short*)(ws + OFF_HBF);
  unsigned short* Wcat   = (unsigned short*)(ws + OFF_WCAT);
  unsigned short* Wge_p  = (unsigned short*)(ws + OFF_WGEP);
  float* lpart  = (float*)(ws + OFF_LPART);
  float* zone   = (float*)(ws + OFF_DEG);
  int*   deg    = (int*)  (ws + OFF_DEG);
  int*   odeg   = (int*)  (ws + OFF_ODEG);
  int*   cursor = (int*)  (ws + OFF_CURS);
  float* P_G    = (float*)(ws + OFF_PG);
  float* P_DG   = (float*)(ws + OFF_PDG);
  float* P_gat  = (float*)(ws + OFF_PGAT);
  float* P_S    = (float*)(ws + OFF_PS);
  float* pe     = (float*)(ws + OFF_PE);
  int*   rowptr = (int*)  (ws + OFF_ROWP);
  int*   csr    = (int*)  (ws + OFF_CSR);
  float* alpha  = (float*)(ws + OFF_ALPHA);
  float* we_loop= (float*)(ws + OFF_WLOOP);
  float* yg     = (float*)(ws + OFF_YG);
  float* pn     = (float*)(ws + OFF_PN);
  float* out_pre= (float*)(ws + OFF_OPRE);

  k_prep0<<<dim3(4340), dim3(256), 0, stream>>>(x, Wn, bn, Wl, Wr, Wge, y, Wg, bg, We, be,
                                                zone, h_bf, Wcat, Wge_p, yg, we_loop);
  k_gemm_xlxr<<<dim3(2048), dim3(256), 0, stream>>>(h_bf, Wcat, bl, br, xl_bf, xr_bf);
  k_prep_e<<<dim3(16704), dim3(256), 0, stream>>>(ea, We, be, E_bf, ei, deg, odeg);
  k_mfma_we<<<dim3(4096), dim3(256), 0, stream>>>(E_bf, Wge_p, ei, xl_bf, xr_bf, att, lpart);
  k_scan<<<dim3(1), dim3(1024), 0, stream>>>(deg, rowptr);
  k_fill_csr<<<dim3(320), dim3(256), 0, stream>>>(ei, rowptr, cursor, csr);
  k_softmax_gat<<<dim3(4096), dim3(256), 0, stream>>>(ei, rowptr, csr, lpart, xl_bf, xr_bf,
                                                      we_loop, att, bgat, alpha, gat_bf);
  k_pool<<<dim3(1792), dim3(256), 0, stream>>>(gat_bf, odeg, rowptr, P_G, P_DG, P_gat,
                                               ea, We, be, alpha, P_S, pe);
  k_pn<<<dim3(512), dim3(256), 0, stream>>>(P_G, P_DG, P_S, P_gat, Wm, bm, Wmi, bmi, Wce, bce,
                                            pn, out_pre);
  k_final<<<dim3(256), dim3(256), 0, stream>>>(pn, pe, yg, W1, b1, W2, out_pre);
  k_sigmoid<<<dim3(1), dim3(32), 0, stream>>>(out_pre, b2, out);
}